// Round 1
// baseline (3692.476 us; speedup 1.0000x reference)
//
#include <hip/hip_runtime.h>

// Problem constants (from reference)
constexpr int Nn = 20000;   // nodes
constexpr int D  = 256;     // feature dim
constexpr int S  = 4;       // snapshots
constexpr int E  = 320000;  // edges
constexpr int H  = 5;       // horizon
constexpr int L  = 3;       // GCN layers

__device__ __forceinline__ float gelu_exact(float x) {
    return 0.5f * x * (1.0f + erff(x * 0.70710678118654752440f));
}

// ---------------- small utility kernels ----------------
__global__ void zero_f_kernel(float* p, int n) {
    int i = blockIdx.x * blockDim.x + threadIdx.x;
    if (i < n) p[i] = 0.0f;
}
__global__ void zero_i_kernel(int* p, int n) {
    int i = blockIdx.x * blockDim.x + threadIdx.x;
    if (i < n) p[i] = 0;
}
__global__ void deg_init_kernel(float* deg, int n) {
    int i = blockIdx.x * blockDim.x + threadIdx.x;
    if (i < n) deg[i] = 1.0f;  // self-loop weight
}
__global__ void deg_edge_kernel(const int* __restrict__ dst, const float* __restrict__ w,
                                float* __restrict__ deg, int e) {
    int i = blockIdx.x * blockDim.x + threadIdx.x;
    if (i < e) atomicAdd(&deg[dst[i]], w[i]);
}
__global__ void dinv_kernel(const float* __restrict__ deg, float* __restrict__ dinv,
                            float* __restrict__ selfnorm, int n) {
    int i = blockIdx.x * blockDim.x + threadIdx.x;
    if (i < n) {
        float dg = deg[i];
        float dv = dg > 0.0f ? rsqrtf(fmaxf(dg, 1e-5f)) : 0.0f;
        dinv[i] = dv;
        selfnorm[i] = dv * dv;
    }
}
__global__ void norm_kernel(const int* __restrict__ src, const int* __restrict__ dst,
                            const float* __restrict__ w, const float* __restrict__ dinv,
                            float* __restrict__ nrm, int e) {
    int i = blockIdx.x * blockDim.x + threadIdx.x;
    if (i < e) nrm[i] = dinv[src[i]] * w[i] * dinv[dst[i]];
}
__global__ void hist_kernel(const int* __restrict__ dst, int* __restrict__ cnt, int e) {
    int i = blockIdx.x * blockDim.x + threadIdx.x;
    if (i < e) atomicAdd(&cnt[dst[i]], 1);
}
// Single-block exclusive scan over cnt[0..n) -> rowptr[0..n]
__global__ __launch_bounds__(256) void scan_rowptr_kernel(const int* __restrict__ cnt,
                                                          int* __restrict__ rowptr, int n) {
    __shared__ int ssum[256];
    int t = threadIdx.x;
    int chunk = (n + 255) / 256;
    int start = t * chunk;
    int end = start + chunk; if (end > n) end = n;
    int s = 0;
    for (int i = start; i < end; ++i) s += cnt[i];
    ssum[t] = s;
    __syncthreads();
    if (t == 0) {
        int acc = 0;
        for (int i = 0; i < 256; ++i) { int v = ssum[i]; ssum[i] = acc; acc += v; }
        rowptr[n] = acc;
    }
    __syncthreads();
    int acc = ssum[t];
    for (int i = start; i < end; ++i) { rowptr[i] = acc; acc += cnt[i]; }
}
__global__ void csr_fill_kernel(const int* __restrict__ src, const int* __restrict__ dst,
                                const float* __restrict__ nrm, const int* __restrict__ rowptr,
                                int* __restrict__ cursor, int* __restrict__ csrc,
                                float* __restrict__ cnorm, int e) {
    int i = blockIdx.x * blockDim.x + threadIdx.x;
    if (i < e) {
        int d = dst[i];
        int pos = rowptr[d] + atomicAdd(&cursor[d], 1);
        csrc[pos] = src[i];
        cnorm[pos] = nrm[i];
    }
}
// Transpose gcn_W[l][k][n] -> Wt[l][n][k]  (so GEMM can run A·B^T everywhere)
__global__ void transpose_w_kernel(const float* __restrict__ W, float* __restrict__ Wt, int total) {
    int i = blockIdx.x * blockDim.x + threadIdx.x;
    if (i < total) {
        int l = i / (D * D);
        int rem = i - l * D * D;
        int k = rem / D;
        int n = rem - k * D;
        Wt[(size_t)l * D * D + (size_t)n * D + k] = W[i];
    }
}

// ---------------- GEMM: C[M,N] = A[M,K] * B[N,K]^T (+bias) (+gelu) ----------------
#define BM 64
#define BN 64
#define BK 16
__global__ __launch_bounds__(256) void gemm_nt_kernel(
    const float* __restrict__ A, const float* __restrict__ B,
    const float* __restrict__ bias, float* __restrict__ C,
    int M, int N, int K, int act)
{
    __shared__ float As[BM][BK + 1];
    __shared__ float Bs[BN][BK + 1];
    int bm = blockIdx.y * BM;
    int bn = blockIdx.x * BN;
    int tid = threadIdx.x;
    int tx = tid & 15;   // n direction
    int ty = tid >> 4;   // m direction
    float acc[4][4] = {{0.f}};

    for (int k0 = 0; k0 < K; k0 += BK) {
        int r  = tid >> 2;           // 0..63
        int kk = (tid & 3) * 4;      // 0,4,8,12
        int gm = bm + r;
        float4 va = make_float4(0.f, 0.f, 0.f, 0.f);
        if (gm < M) va = *(const float4*)(A + (size_t)gm * K + k0 + kk);
        As[r][kk + 0] = va.x; As[r][kk + 1] = va.y; As[r][kk + 2] = va.z; As[r][kk + 3] = va.w;
        int gn = bn + r;
        float4 vb = make_float4(0.f, 0.f, 0.f, 0.f);
        if (gn < N) vb = *(const float4*)(B + (size_t)gn * K + k0 + kk);
        Bs[r][kk + 0] = vb.x; Bs[r][kk + 1] = vb.y; Bs[r][kk + 2] = vb.z; Bs[r][kk + 3] = vb.w;
        __syncthreads();
#pragma unroll
        for (int kk2 = 0; kk2 < BK; ++kk2) {
            float a[4], b[4];
#pragma unroll
            for (int i = 0; i < 4; ++i) a[i] = As[ty * 4 + i][kk2];
#pragma unroll
            for (int j = 0; j < 4; ++j) b[j] = Bs[tx * 4 + j][kk2];
#pragma unroll
            for (int i = 0; i < 4; ++i)
#pragma unroll
                for (int j = 0; j < 4; ++j)
                    acc[i][j] = fmaf(a[i], b[j], acc[i][j]);
        }
        __syncthreads();
    }
#pragma unroll
    for (int i = 0; i < 4; ++i) {
        int gm = bm + ty * 4 + i;
        if (gm >= M) continue;
#pragma unroll
        for (int j = 0; j < 4; ++j) {
            int gn = bn + tx * 4 + j;
            if (gn >= N) continue;
            float v = acc[i][j];
            if (bias) v += bias[gn];
            if (act == 1) v = gelu_exact(v);
            C[(size_t)gm * N + gn] = v;
        }
    }
}

// ---------------- GCN aggregate + bias + LayerNorm + ReLU (one block per node) ----------------
__global__ __launch_bounds__(256) void gcn_agg_ln_relu_kernel(
    const float* __restrict__ hW, const int* __restrict__ rowptr,
    const int* __restrict__ csrc, const float* __restrict__ cnorm,
    const float* __restrict__ selfnorm,
    const float* __restrict__ gcn_b, const float* __restrict__ ln_g,
    const float* __restrict__ ln_b, float* __restrict__ out)
{
    int i = blockIdx.x;
    int d = threadIdx.x;
    float acc = selfnorm[i] * hW[(size_t)i * D + d];
    int beg = rowptr[i], end = rowptr[i + 1];
    for (int p = beg; p < end; ++p) {
        int s = csrc[p];
        acc = fmaf(cnorm[p], hW[(size_t)s * D + d], acc);
    }
    acc += gcn_b[d];
    __shared__ float s1[256];
    __shared__ float s2[256];
    s1[d] = acc; s2[d] = acc * acc;
    __syncthreads();
    for (int st = 128; st > 0; st >>= 1) {
        if (d < st) { s1[d] += s1[d + st]; s2[d] += s2[d + st]; }
        __syncthreads();
    }
    float m = s1[0] * (1.0f / D);
    float v = s2[0] * (1.0f / D) - m * m;
    float y = (acc - m) * rsqrtf(v + 1e-5f) * ln_g[d] + ln_b[d];
    out[(size_t)i * D + d] = fmaxf(y, 0.0f);
}

// ---------------- GRU gate elementwise ----------------
__global__ void gru_gates_kernel(const float* __restrict__ gi, const float* __restrict__ gh,
                                 float* __restrict__ h, int n) {
    int idx = blockIdx.x * blockDim.x + threadIdx.x;
    if (idx >= n) return;
    int i = idx >> 8;       // / D
    int d = idx & 255;      // % D
    const float* gir = gi + (size_t)i * 3 * D;
    const float* ghr = gh + (size_t)i * 3 * D;
    float ir = gir[d], iz = gir[D + d], ig = gir[2 * D + d];
    float hr = ghr[d], hz = ghr[D + d], hg = ghr[2 * D + d];
    float r = 1.0f / (1.0f + expf(-(ir + hr)));
    float z = 1.0f / (1.0f + expf(-(iz + hz)));
    float nn = tanhf(ig + r * hg);
    h[idx] = (1.0f - z) * nn + z * h[idx];
}

// ---------------- small output head: C[M,5] = A[M,K] * W[5,K]^T + b ----------------
__global__ void head5_kernel(const float* __restrict__ A, const float* __restrict__ W,
                             const float* __restrict__ b, float* __restrict__ C,
                             int M, int K) {
    int idx = blockIdx.x * blockDim.x + threadIdx.x;
    if (idx >= M * H) return;
    int m = idx / H;
    int h = idx - m * H;
    const float* ar = A + (size_t)m * K;
    const float* wr = W + (size_t)h * K;
    float s = 0.0f;
    for (int k = 0; k < K; ++k) s = fmaf(ar[k], wr[k], s);
    C[idx] = s + b[h];
}

extern "C" void kernel_launch(void* const* d_in, const int* in_sizes, int n_in,
                              void* d_out, int out_size, void* d_ws, size_t ws_size,
                              hipStream_t stream)
{
    const float* x     = (const float*)d_in[0];
    const int*   esrc  = (const int*)d_in[1];
    const int*   edst  = (const int*)d_in[2];
    const float* ew    = (const float*)d_in[3];
    const float* gcn_W = (const float*)d_in[4];
    const float* gcn_b = (const float*)d_in[5];
    const float* ln_g  = (const float*)d_in[6];
    const float* ln_b  = (const float*)d_in[7];
    const float* Wih   = (const float*)d_in[8];
    const float* Whh   = (const float*)d_in[9];
    const float* bih   = (const float*)d_in[10];
    const float* bhh   = (const float*)d_in[11];
    const float* fc1W  = (const float*)d_in[12];
    const float* fc1b  = (const float*)d_in[13];
    const float* fc2W  = (const float*)d_in[14];
    const float* fc2b  = (const float*)d_in[15];
    const float* fc3W  = (const float*)d_in[16];
    const float* fc3b  = (const float*)d_in[17];
    const float* dh1W  = (const float*)d_in[18];
    const float* dh1b  = (const float*)d_in[19];
    const float* dh2W  = (const float*)d_in[20];
    const float* dh2b  = (const float*)d_in[21];

    float* out = (float*)d_out;   // [Nn*H forecast][Nn*H direction]

    // workspace carve-out (aligned to 256B)
    char* p = (char*)d_ws;
    auto alloc = [&](size_t bytes) -> void* {
        void* r = (void*)p;
        p += (bytes + 255) & ~(size_t)255;
        return r;
    };
    float* deg      = (float*)alloc((size_t)Nn * 4);
    float* dinv     = (float*)alloc((size_t)Nn * 4);
    float* selfnorm = (float*)alloc((size_t)Nn * 4);
    float* nrm      = (float*)alloc((size_t)E * 4);
    int*   rowptr   = (int*)alloc((size_t)(Nn + 1) * 4);
    int*   cnt      = (int*)alloc((size_t)Nn * 4);
    int*   csrc     = (int*)alloc((size_t)E * 4);
    float* cnorm    = (float*)alloc((size_t)E * 4);
    float* Wt       = (float*)alloc((size_t)L * D * D * 4);
    float* hbuf     = (float*)alloc((size_t)Nn * D * 4);
    float* tmp      = (float*)alloc((size_t)Nn * D * 4);
    float* hgru     = (float*)alloc((size_t)Nn * D * 4);
    float* gi       = (float*)alloc((size_t)Nn * 3 * D * 4);
    float* gh       = (float*)alloc((size_t)Nn * 3 * D * 4);
    // head scratch aliases (gi/gh free after GRU)
    float* f1 = gi;               // [Nn,128]
    float* f2 = gi + (size_t)Nn * 128;  // [Nn,64]
    float* d1 = gh;               // [Nn,64]

    auto cdiv = [](int a, int b) { return (a + b - 1) / b; };

    // ---- graph preprocessing (per call; inputs restored each launch) ----
    zero_i_kernel<<<cdiv(Nn, 256), 256, 0, stream>>>(cnt, Nn);
    deg_init_kernel<<<cdiv(Nn, 256), 256, 0, stream>>>(deg, Nn);
    deg_edge_kernel<<<cdiv(E, 256), 256, 0, stream>>>(edst, ew, deg, E);
    dinv_kernel<<<cdiv(Nn, 256), 256, 0, stream>>>(deg, dinv, selfnorm, Nn);
    norm_kernel<<<cdiv(E, 256), 256, 0, stream>>>(esrc, edst, ew, dinv, nrm, E);
    hist_kernel<<<cdiv(E, 256), 256, 0, stream>>>(edst, cnt, E);
    scan_rowptr_kernel<<<1, 256, 0, stream>>>(cnt, rowptr, Nn);
    zero_i_kernel<<<cdiv(Nn, 256), 256, 0, stream>>>(cnt, Nn);
    csr_fill_kernel<<<cdiv(E, 256), 256, 0, stream>>>(esrc, edst, nrm, rowptr, cnt, csrc, cnorm, E);
    transpose_w_kernel<<<cdiv(L * D * D, 256), 256, 0, stream>>>(gcn_W, Wt, L * D * D);
    zero_f_kernel<<<cdiv(Nn * D, 256), 256, 0, stream>>>(hgru, Nn * D);

    auto gemm = [&](const float* A, const float* B, const float* bias, float* C,
                    int M, int Ncols, int K, int act) {
        dim3 g(cdiv(Ncols, BN), cdiv(M, BM));
        gemm_nt_kernel<<<g, 256, 0, stream>>>(A, B, bias, C, M, Ncols, K, act);
    };

    // ---- per-snapshot GCN stack + GRU step ----
    for (int s = 0; s < S; ++s) {
        const float* hin = x + (size_t)s * Nn * D;
        for (int l = 0; l < L; ++l) {
            const float* a = (l == 0) ? hin : hbuf;
            gemm(a, Wt + (size_t)l * D * D, nullptr, tmp, Nn, D, D, 0);  // hW
            gcn_agg_ln_relu_kernel<<<Nn, 256, 0, stream>>>(
                tmp, rowptr, csrc, cnorm, selfnorm,
                gcn_b + (size_t)l * D, ln_g + (size_t)l * D, ln_b + (size_t)l * D, hbuf);
        }
        // GRU step: gi = hbuf @ Wih^T + bih ; gh = hgru @ Whh^T + bhh
        gemm(hbuf, Wih, bih, gi, Nn, 3 * D, D, 0);
        gemm(hgru, Whh, bhh, gh, Nn, 3 * D, D, 0);
        gru_gates_kernel<<<cdiv(Nn * D, 256), 256, 0, stream>>>(gi, gh, hgru, Nn * D);
    }

    // ---- heads ----
    gemm(hgru, fc1W, fc1b, f1, Nn, 128, 256, 1);     // gelu
    gemm(f1,   fc2W, fc2b, f2, Nn, 64, 128, 1);      // gelu
    head5_kernel<<<cdiv(Nn * H, 256), 256, 0, stream>>>(f2, fc3W, fc3b, out, Nn, 64);
    gemm(hgru, dh1W, dh1b, d1, Nn, 64, 256, 1);      // gelu
    head5_kernel<<<cdiv(Nn * H, 256), 256, 0, stream>>>(d1, dh2W, dh2b, out + (size_t)Nn * H, Nn, 64);
}

// Round 2
// 1934.609 us; speedup vs baseline: 1.9086x; 1.9086x over previous
//
#include <hip/hip_runtime.h>
#include <hip/hip_bf16.h>

// Problem constants (from reference)
constexpr int Nn = 20000;   // nodes
constexpr int D  = 256;     // feature dim
constexpr int S  = 4;       // snapshots
constexpr int E  = 320000;  // edges
constexpr int H  = 5;       // horizon
constexpr int L  = 3;       // GCN layers

using bf16 = __hip_bfloat16;
typedef __attribute__((ext_vector_type(8))) short v8s;   // 8 bf16 = 4 VGPRs
typedef __attribute__((ext_vector_type(4))) float v4f;   // MFMA acc

#define GLOBAL_AS __attribute__((address_space(1)))
#define LDS_AS    __attribute__((address_space(3)))

__device__ __forceinline__ float gelu_exact(float x) {
    return 0.5f * x * (1.0f + erff(x * 0.70710678118654752440f));
}

// ---------------- small utility kernels ----------------
__global__ void zero_f_kernel(float* p, int n) {
    int i = blockIdx.x * blockDim.x + threadIdx.x;
    if (i < n) p[i] = 0.0f;
}
__global__ void zero_b_kernel(unsigned short* p, int n) {
    int i = blockIdx.x * blockDim.x + threadIdx.x;
    if (i < n) p[i] = 0;
}
__global__ void zero_i_kernel(int* p, int n) {
    int i = blockIdx.x * blockDim.x + threadIdx.x;
    if (i < n) p[i] = 0;
}
__global__ void f2b_kernel(const float* __restrict__ in, bf16* __restrict__ out, int n) {
    int i = blockIdx.x * blockDim.x + threadIdx.x;
    if (i < n) out[i] = __float2bfloat16(in[i]);
}
__global__ void deg_init_kernel(float* deg, int n) {
    int i = blockIdx.x * blockDim.x + threadIdx.x;
    if (i < n) deg[i] = 1.0f;  // self-loop weight
}
__global__ void deg_edge_kernel(const int* __restrict__ dst, const float* __restrict__ w,
                                float* __restrict__ deg, int e) {
    int i = blockIdx.x * blockDim.x + threadIdx.x;
    if (i < e) atomicAdd(&deg[dst[i]], w[i]);
}
__global__ void dinv_kernel(const float* __restrict__ deg, float* __restrict__ dinv,
                            float* __restrict__ selfnorm, int n) {
    int i = blockIdx.x * blockDim.x + threadIdx.x;
    if (i < n) {
        float dg = deg[i];
        float dv = dg > 0.0f ? rsqrtf(fmaxf(dg, 1e-5f)) : 0.0f;
        dinv[i] = dv;
        selfnorm[i] = dv * dv;
    }
}
__global__ void hist_kernel(const int* __restrict__ dst, int* __restrict__ cnt, int e) {
    int i = blockIdx.x * blockDim.x + threadIdx.x;
    if (i < e) atomicAdd(&cnt[dst[i]], 1);
}
// Single-block exclusive scan over cnt[0..n) -> rowptr[0..n]
__global__ __launch_bounds__(256) void scan_rowptr_kernel(const int* __restrict__ cnt,
                                                          int* __restrict__ rowptr, int n) {
    __shared__ int ssum[256];
    int t = threadIdx.x;
    int chunk = (n + 255) / 256;
    int start = t * chunk;
    int end = start + chunk; if (end > n) end = n;
    int s = 0;
    for (int i = start; i < end; ++i) s += cnt[i];
    ssum[t] = s;
    __syncthreads();
    if (t == 0) {
        int acc = 0;
        for (int i = 0; i < 256; ++i) { int v = ssum[i]; ssum[i] = acc; acc += v; }
        rowptr[n] = acc;
    }
    __syncthreads();
    int acc = ssum[t];
    for (int i = start; i < end; ++i) { rowptr[i] = acc; acc += cnt[i]; }
}
// fill CSR, computing edge norm inline: nrm = dinv[src]*w*dinv[dst]
__global__ void csr_fill_kernel(const int* __restrict__ src, const int* __restrict__ dst,
                                const float* __restrict__ w, const float* __restrict__ dinv,
                                const int* __restrict__ rowptr,
                                int* __restrict__ cursor, int* __restrict__ csrc,
                                float* __restrict__ cnorm, int e) {
    int i = blockIdx.x * blockDim.x + threadIdx.x;
    if (i < e) {
        int sN = src[i], dN = dst[i];
        int pos = rowptr[dN] + atomicAdd(&cursor[dN], 1);
        csrc[pos] = sN;
        cnorm[pos] = dinv[sN] * w[i] * dinv[dN];
    }
}
// Transpose gcn_W[l][k][n] -> Wt[l][n][k] bf16 (so GEMM runs A·B^T everywhere)
__global__ void transpose_w_kernel(const float* __restrict__ W, bf16* __restrict__ Wt, int total) {
    int i = blockIdx.x * blockDim.x + threadIdx.x;
    if (i < total) {
        int l = i / (D * D);
        int rem = i - l * D * D;
        int k = rem / D;
        int n = rem - k * D;
        Wt[(size_t)l * D * D + (size_t)n * D + k] = __float2bfloat16(W[i]);
    }
}

// ---------------- bf16 MFMA GEMM: C[M,N] = A[M,K] * B[N,K]^T (+bias), f32 out ----
// 128x128 block tile, BK=64, 4 waves in 2x2, each wave 64x64 via 4x4 MFMA 16x16x32.
// LDS unpadded row-major [row][BK] (global_load_lds requires lane-contiguous dest).
// Requires: K % 64 == 0, N % 128 == 0. M guarded by clamping load rows / store mask.
#define GBM 128
#define GBN 128
#define GBK 64
__global__ __launch_bounds__(256) void gemm_bt_bf16_kernel(
    const bf16* __restrict__ A, const bf16* __restrict__ B,
    const float* __restrict__ bias, float* __restrict__ C,
    int M, int N, int K)
{
    __shared__ short As[GBM * GBK];
    __shared__ short Bs[GBN * GBK];
    int tid = threadIdx.x;
    int wave = tid >> 6, lane = tid & 63;
    int ln = lane & 15, quad = lane >> 4;
    int wr = wave >> 1, wc = wave & 1;
    int bm = blockIdx.y * GBM, bn = blockIdx.x * GBN;

    v4f acc[4][4];
#pragma unroll
    for (int i = 0; i < 4; ++i)
#pragma unroll
        for (int j = 0; j < 4; ++j)
            acc[i][j] = (v4f)(0.0f);

    int lrow = lane >> 3;          // 0..7 within 8-row segment
    int lcol = (lane & 7) * 8;     // bf16 col offset, 16B chunks

    for (int k0 = 0; k0 < K; k0 += GBK) {
#pragma unroll
        for (int c = 0; c < 4; ++c) {
            int seg = wave * 4 + c;           // 0..15
            int row = seg * 8 + lrow;         // 0..127
            int gm = bm + row; if (gm >= M) gm = M - 1;   // clamp: dup rows, rows>=M never stored
            __builtin_amdgcn_global_load_lds(
                (const GLOBAL_AS unsigned int*)(A + (size_t)gm * K + k0 + lcol),
                (LDS_AS unsigned int*)(&As[row * GBK + lcol]), 16, 0, 0);
            int gn = bn + row;                // N % 128 == 0, no clamp needed
            __builtin_amdgcn_global_load_lds(
                (const GLOBAL_AS unsigned int*)(B + (size_t)gn * K + k0 + lcol),
                (LDS_AS unsigned int*)(&Bs[row * GBK + lcol]), 16, 0, 0);
        }
        __syncthreads();
#pragma unroll
        for (int ks = 0; ks < 2; ++ks) {
            v8s af[4], bfr[4];
#pragma unroll
            for (int i = 0; i < 4; ++i) {
                int row = wr * 64 + i * 16 + ln;
                af[i] = *(const v8s*)(&As[row * GBK + ks * 32 + quad * 8]);
            }
#pragma unroll
            for (int j = 0; j < 4; ++j) {
                int row = wc * 64 + j * 16 + ln;
                bfr[j] = *(const v8s*)(&Bs[row * GBK + ks * 32 + quad * 8]);
            }
#pragma unroll
            for (int i = 0; i < 4; ++i)
#pragma unroll
                for (int j = 0; j < 4; ++j)
                    acc[i][j] = __builtin_amdgcn_mfma_f32_16x16x32_bf16(af[i], bfr[j], acc[i][j], 0, 0, 0);
        }
        __syncthreads();
    }
    // epilogue: C/D layout col=lane&15, row=quad*4+reg
#pragma unroll
    for (int i = 0; i < 4; ++i) {
#pragma unroll
        for (int r = 0; r < 4; ++r) {
            int gm = bm + wr * 64 + i * 16 + quad * 4 + r;
            if (gm >= M) continue;
#pragma unroll
            for (int j = 0; j < 4; ++j) {
                int gn = bn + wc * 64 + j * 16 + ln;
                float v = acc[i][j][r];
                if (bias) v += bias[gn];
                C[(size_t)gm * N + gn] = v;
            }
        }
    }
}

// ---------------- fp32 GEMM (heads only): C[M,N] = A[M,K]*B[N,K]^T (+bias)(+gelu) --
#define BM 64
#define BN 64
#define BK 16
__global__ __launch_bounds__(256) void gemm_nt_kernel(
    const float* __restrict__ A, const float* __restrict__ B,
    const float* __restrict__ bias, float* __restrict__ C,
    int M, int N, int K, int act)
{
    __shared__ float As[BM][BK + 1];
    __shared__ float Bs[BN][BK + 1];
    int bm = blockIdx.y * BM;
    int bn = blockIdx.x * BN;
    int tid = threadIdx.x;
    int tx = tid & 15;
    int ty = tid >> 4;
    float acc[4][4] = {{0.f}};

    for (int k0 = 0; k0 < K; k0 += BK) {
        int r  = tid >> 2;
        int kk = (tid & 3) * 4;
        int gm = bm + r;
        float4 va = make_float4(0.f, 0.f, 0.f, 0.f);
        if (gm < M) va = *(const float4*)(A + (size_t)gm * K + k0 + kk);
        As[r][kk + 0] = va.x; As[r][kk + 1] = va.y; As[r][kk + 2] = va.z; As[r][kk + 3] = va.w;
        int gn = bn + r;
        float4 vb = make_float4(0.f, 0.f, 0.f, 0.f);
        if (gn < N) vb = *(const float4*)(B + (size_t)gn * K + k0 + kk);
        Bs[r][kk + 0] = vb.x; Bs[r][kk + 1] = vb.y; Bs[r][kk + 2] = vb.z; Bs[r][kk + 3] = vb.w;
        __syncthreads();
#pragma unroll
        for (int kk2 = 0; kk2 < BK; ++kk2) {
            float a[4], b[4];
#pragma unroll
            for (int i = 0; i < 4; ++i) a[i] = As[ty * 4 + i][kk2];
#pragma unroll
            for (int j = 0; j < 4; ++j) b[j] = Bs[tx * 4 + j][kk2];
#pragma unroll
            for (int i = 0; i < 4; ++i)
#pragma unroll
                for (int j = 0; j < 4; ++j)
                    acc[i][j] = fmaf(a[i], b[j], acc[i][j]);
        }
        __syncthreads();
    }
#pragma unroll
    for (int i = 0; i < 4; ++i) {
        int gm = bm + ty * 4 + i;
        if (gm >= M) continue;
#pragma unroll
        for (int j = 0; j < 4; ++j) {
            int gn = bn + tx * 4 + j;
            if (gn >= N) continue;
            float v = acc[i][j];
            if (bias) v += bias[gn];
            if (act == 1) v = gelu_exact(v);
            C[(size_t)gm * N + gn] = v;
        }
    }
}

// ------- GCN aggregate + bias + LayerNorm + ReLU (one block per node), bf16 out ----
__global__ __launch_bounds__(256) void gcn_agg_ln_relu_kernel(
    const float* __restrict__ hW, const int* __restrict__ rowptr,
    const int* __restrict__ csrc, const float* __restrict__ cnorm,
    const float* __restrict__ selfnorm,
    const float* __restrict__ gcn_b, const float* __restrict__ ln_g,
    const float* __restrict__ ln_b, bf16* __restrict__ out)
{
    int i = blockIdx.x;
    int d = threadIdx.x;
    float acc = selfnorm[i] * hW[(size_t)i * D + d];
    int beg = rowptr[i], end = rowptr[i + 1];
    for (int p = beg; p < end; ++p) {
        int s = csrc[p];
        acc = fmaf(cnorm[p], hW[(size_t)s * D + d], acc);
    }
    acc += gcn_b[d];
    __shared__ float s1[256];
    __shared__ float s2[256];
    s1[d] = acc; s2[d] = acc * acc;
    __syncthreads();
    for (int st = 128; st > 0; st >>= 1) {
        if (d < st) { s1[d] += s1[d + st]; s2[d] += s2[d + st]; }
        __syncthreads();
    }
    float m = s1[0] * (1.0f / D);
    float v = s2[0] * (1.0f / D) - m * m;
    float y = (acc - m) * rsqrtf(v + 1e-5f) * ln_g[d] + ln_b[d];
    out[(size_t)i * D + d] = __float2bfloat16(fmaxf(y, 0.0f));
}

// ---------------- GRU gate elementwise: h f32 + bf16 copy ----------------
__global__ void gru_gates_kernel(const float* __restrict__ gi, const float* __restrict__ gh,
                                 float* __restrict__ h, bf16* __restrict__ hb, int n) {
    int idx = blockIdx.x * blockDim.x + threadIdx.x;
    if (idx >= n) return;
    int i = idx >> 8;       // / D
    int d = idx & 255;      // % D
    const float* gir = gi + (size_t)i * 3 * D;
    const float* ghr = gh + (size_t)i * 3 * D;
    float ir = gir[d], iz = gir[D + d], ig = gir[2 * D + d];
    float hr = ghr[d], hz = ghr[D + d], hg = ghr[2 * D + d];
    float r = 1.0f / (1.0f + expf(-(ir + hr)));
    float z = 1.0f / (1.0f + expf(-(iz + hz)));
    float nn = tanhf(ig + r * hg);
    float hv = (1.0f - z) * nn + z * h[idx];
    h[idx] = hv;
    hb[idx] = __float2bfloat16(hv);
}

// ---------------- small output head: C[M,5] = A[M,K] * W[5,K]^T + b ----------------
__global__ void head5_kernel(const float* __restrict__ A, const float* __restrict__ W,
                             const float* __restrict__ b, float* __restrict__ C,
                             int M, int K) {
    int idx = blockIdx.x * blockDim.x + threadIdx.x;
    if (idx >= M * H) return;
    int m = idx / H;
    int h = idx - m * H;
    const float* ar = A + (size_t)m * K;
    const float* wr = W + (size_t)h * K;
    float s = 0.0f;
    for (int k = 0; k < K; ++k) s = fmaf(ar[k], wr[k], s);
    C[idx] = s + b[h];
}

extern "C" void kernel_launch(void* const* d_in, const int* in_sizes, int n_in,
                              void* d_out, int out_size, void* d_ws, size_t ws_size,
                              hipStream_t stream)
{
    const float* x     = (const float*)d_in[0];
    const int*   esrc  = (const int*)d_in[1];
    const int*   edst  = (const int*)d_in[2];
    const float* ew    = (const float*)d_in[3];
    const float* gcn_W = (const float*)d_in[4];
    const float* gcn_b = (const float*)d_in[5];
    const float* ln_g  = (const float*)d_in[6];
    const float* ln_b  = (const float*)d_in[7];
    const float* Wih   = (const float*)d_in[8];
    const float* Whh   = (const float*)d_in[9];
    const float* bih   = (const float*)d_in[10];
    const float* bhh   = (const float*)d_in[11];
    const float* fc1W  = (const float*)d_in[12];
    const float* fc1b  = (const float*)d_in[13];
    const float* fc2W  = (const float*)d_in[14];
    const float* fc2b  = (const float*)d_in[15];
    const float* fc3W  = (const float*)d_in[16];
    const float* fc3b  = (const float*)d_in[17];
    const float* dh1W  = (const float*)d_in[18];
    const float* dh1b  = (const float*)d_in[19];
    const float* dh2W  = (const float*)d_in[20];
    const float* dh2b  = (const float*)d_in[21];

    float* out = (float*)d_out;   // [Nn*H forecast][Nn*H direction]

    // workspace carve-out (aligned to 256B)
    char* p = (char*)d_ws;
    auto alloc = [&](size_t bytes) -> void* {
        void* r = (void*)p;
        p += (bytes + 255) & ~(size_t)255;
        return r;
    };
    float* deg      = (float*)alloc((size_t)Nn * 4);
    float* dinv     = (float*)alloc((size_t)Nn * 4);
    float* selfnorm = (float*)alloc((size_t)Nn * 4);
    int*   rowptr   = (int*)alloc((size_t)(Nn + 1) * 4);
    int*   cnt      = (int*)alloc((size_t)Nn * 4);
    int*   csrc     = (int*)alloc((size_t)E * 4);
    float* cnorm    = (float*)alloc((size_t)E * 4);
    bf16*  Wtb      = (bf16*)alloc((size_t)L * D * D * 2);
    bf16*  Wihb     = (bf16*)alloc((size_t)3 * D * D * 2);
    bf16*  Whhb     = (bf16*)alloc((size_t)3 * D * D * 2);
    bf16*  hbuf_bf  = (bf16*)alloc((size_t)Nn * D * 2);   // doubles as x_s bf16 staging
    float* tmp      = (float*)alloc((size_t)Nn * D * 4);  // hW f32 (GEMM C out)
    float* hgru     = (float*)alloc((size_t)Nn * D * 4);
    bf16*  hgru_bf  = (bf16*)alloc((size_t)Nn * D * 2);
    float* gi       = (float*)alloc((size_t)Nn * 3 * D * 4);
    float* gh       = (float*)alloc((size_t)Nn * 3 * D * 4);
    // head scratch aliases (gi/gh free after GRU)
    float* f1 = gi;                      // [Nn,128]
    float* f2 = gi + (size_t)Nn * 128;   // [Nn,64]
    float* d1 = gh;                      // [Nn,64]

    auto cdiv = [](int a, int b) { return (a + b - 1) / b; };

    // ---- graph preprocessing ----
    zero_i_kernel<<<cdiv(Nn, 256), 256, 0, stream>>>(cnt, Nn);
    deg_init_kernel<<<cdiv(Nn, 256), 256, 0, stream>>>(deg, Nn);
    deg_edge_kernel<<<cdiv(E, 256), 256, 0, stream>>>(edst, ew, deg, E);
    dinv_kernel<<<cdiv(Nn, 256), 256, 0, stream>>>(deg, dinv, selfnorm, Nn);
    hist_kernel<<<cdiv(E, 256), 256, 0, stream>>>(edst, cnt, E);
    scan_rowptr_kernel<<<1, 256, 0, stream>>>(cnt, rowptr, Nn);
    zero_i_kernel<<<cdiv(Nn, 256), 256, 0, stream>>>(cnt, Nn);
    csr_fill_kernel<<<cdiv(E, 256), 256, 0, stream>>>(esrc, edst, ew, dinv, rowptr, cnt, csrc, cnorm, E);
    transpose_w_kernel<<<cdiv(L * D * D, 256), 256, 0, stream>>>(gcn_W, Wtb, L * D * D);
    f2b_kernel<<<cdiv(3 * D * D, 256), 256, 0, stream>>>(Wih, Wihb, 3 * D * D);
    f2b_kernel<<<cdiv(3 * D * D, 256), 256, 0, stream>>>(Whh, Whhb, 3 * D * D);
    zero_f_kernel<<<cdiv(Nn * D, 256), 256, 0, stream>>>(hgru, Nn * D);
    zero_b_kernel<<<cdiv(Nn * D, 256), 256, 0, stream>>>((unsigned short*)hgru_bf, Nn * D);

    auto gemm_bf = [&](const bf16* A, const bf16* B, const float* bias, float* C,
                       int M, int Ncols, int K) {
        dim3 g(Ncols / GBN, cdiv(M, GBM));
        gemm_bt_bf16_kernel<<<g, 256, 0, stream>>>(A, B, bias, C, M, Ncols, K);
    };
    auto gemm_f = [&](const float* A, const float* B, const float* bias, float* C,
                      int M, int Ncols, int K, int act) {
        dim3 g(cdiv(Ncols, BN), cdiv(M, BM));
        gemm_nt_kernel<<<g, 256, 0, stream>>>(A, B, bias, C, M, Ncols, K, act);
    };

    // ---- per-snapshot GCN stack + GRU step ----
    for (int s = 0; s < S; ++s) {
        // x_s -> bf16 into hbuf_bf (prev snapshot's hbuf_bf already consumed)
        f2b_kernel<<<cdiv(Nn * D, 256), 256, 0, stream>>>(x + (size_t)s * Nn * D, hbuf_bf, Nn * D);
        for (int l = 0; l < L; ++l) {
            gemm_bf(hbuf_bf, Wtb + (size_t)l * D * D, nullptr, tmp, Nn, D, D);   // hW
            gcn_agg_ln_relu_kernel<<<Nn, 256, 0, stream>>>(
                tmp, rowptr, csrc, cnorm, selfnorm,
                gcn_b + (size_t)l * D, ln_g + (size_t)l * D, ln_b + (size_t)l * D, hbuf_bf);
        }
        // GRU step
        gemm_bf(hbuf_bf, Wihb, bih, gi, Nn, 3 * D, D);
        gemm_bf(hgru_bf, Whhb, bhh, gh, Nn, 3 * D, D);
        gru_gates_kernel<<<cdiv(Nn * D, 256), 256, 0, stream>>>(gi, gh, hgru, hgru_bf, Nn * D);
    }

    // ---- heads (f32) ----
    gemm_f(hgru, fc1W, fc1b, f1, Nn, 128, 256, 1);     // gelu
    gemm_f(f1,   fc2W, fc2b, f2, Nn, 64, 128, 1);      // gelu
    head5_kernel<<<cdiv(Nn * H, 256), 256, 0, stream>>>(f2, fc3W, fc3b, out, Nn, 64);
    gemm_f(hgru, dh1W, dh1b, d1, Nn, 64, 256, 1);      // gelu
    head5_kernel<<<cdiv(Nn * H, 256), 256, 0, stream>>>(d1, dh2W, dh2b, out + (size_t)Nn * H, Nn, 64);
}

// Round 3
// 1165.221 us; speedup vs baseline: 3.1689x; 1.6603x over previous
//
#include <hip/hip_runtime.h>
#include <hip/hip_bf16.h>

// Problem constants (from reference)
constexpr int Nn = 20000;   // nodes
constexpr int D  = 256;     // feature dim
constexpr int S  = 4;       // snapshots
constexpr int E  = 320000;  // edges
constexpr int H  = 5;       // horizon
constexpr int L  = 3;       // GCN layers

using bf16 = __hip_bfloat16;
typedef __attribute__((ext_vector_type(8))) short v8s;   // 8 bf16 = 4 VGPRs
typedef __attribute__((ext_vector_type(4))) float v4f;   // MFMA acc

#define GLOBAL_AS __attribute__((address_space(1)))
#define LDS_AS    __attribute__((address_space(3)))

__device__ __forceinline__ float gelu_exact(float x) {
    return 0.5f * x * (1.0f + erff(x * 0.70710678118654752440f));
}
__device__ __forceinline__ unsigned short f2bu(float f) {
    bf16 h = __float2bfloat16(f);
    return *reinterpret_cast<unsigned short*>(&h);
}
__device__ __forceinline__ float b2f(unsigned short u) {
    unsigned int v = (unsigned int)u << 16;
    return __uint_as_float(v);
}

// ---------------- small utility kernels ----------------
__global__ void zero_f_kernel(float* p, int n) {
    int i = blockIdx.x * blockDim.x + threadIdx.x;
    if (i < n) p[i] = 0.0f;
}
__global__ void zero_b_kernel(unsigned short* p, int n) {
    int i = blockIdx.x * blockDim.x + threadIdx.x;
    if (i < n) p[i] = 0;
}
__global__ void zero_i_kernel(int* p, int n) {
    int i = blockIdx.x * blockDim.x + threadIdx.x;
    if (i < n) p[i] = 0;
}
__global__ void f2b_kernel(const float* __restrict__ in, unsigned short* __restrict__ out, int n) {
    int i = blockIdx.x * blockDim.x + threadIdx.x;
    if (i < n) out[i] = f2bu(in[i]);
}
// x [S,N,D] f32 -> blocked [n*S+s][D] bf16
__global__ __launch_bounds__(256) void x_to_blocked_kernel(const float* __restrict__ x,
                                                           unsigned short* __restrict__ out) {
    int b = blockIdx.x;              // n*S+s
    int d = threadIdx.x;
    int n = b >> 2, s = b & 3;
    float v = x[((size_t)s * Nn + n) * D + d];
    out[(size_t)b * D + d] = f2bu(v);
}
__global__ void deg_init_kernel(float* deg, int n) {
    int i = blockIdx.x * blockDim.x + threadIdx.x;
    if (i < n) deg[i] = 1.0f;  // self-loop weight
}
__global__ void deg_edge_kernel(const int* __restrict__ dst, const float* __restrict__ w,
                                float* __restrict__ deg, int e) {
    int i = blockIdx.x * blockDim.x + threadIdx.x;
    if (i < e) atomicAdd(&deg[dst[i]], w[i]);
}
__global__ void dinv_kernel(const float* __restrict__ deg, float* __restrict__ dinv,
                            float* __restrict__ selfnorm, int n) {
    int i = blockIdx.x * blockDim.x + threadIdx.x;
    if (i < n) {
        float dg = deg[i];
        float dv = dg > 0.0f ? rsqrtf(fmaxf(dg, 1e-5f)) : 0.0f;
        dinv[i] = dv;
        selfnorm[i] = dv * dv;
    }
}
__global__ void hist_kernel(const int* __restrict__ dst, int* __restrict__ cnt, int e) {
    int i = blockIdx.x * blockDim.x + threadIdx.x;
    if (i < e) atomicAdd(&cnt[dst[i]], 1);
}
// Single-block exclusive scan over cnt[0..n) -> rowptr[0..n]
__global__ __launch_bounds__(256) void scan_rowptr_kernel(const int* __restrict__ cnt,
                                                          int* __restrict__ rowptr, int n) {
    __shared__ int ssum[256];
    int t = threadIdx.x;
    int chunk = (n + 255) / 256;
    int start = t * chunk;
    int end = start + chunk; if (end > n) end = n;
    int s = 0;
    for (int i = start; i < end; ++i) s += cnt[i];
    ssum[t] = s;
    __syncthreads();
    if (t == 0) {
        int acc = 0;
        for (int i = 0; i < 256; ++i) { int v = ssum[i]; ssum[i] = acc; acc += v; }
        rowptr[n] = acc;
    }
    __syncthreads();
    int acc = ssum[t];
    for (int i = start; i < end; ++i) { rowptr[i] = acc; acc += cnt[i]; }
}
// fill CSR, computing edge norm inline: nrm = dinv[src]*w*dinv[dst]
__global__ void csr_fill_kernel(const int* __restrict__ src, const int* __restrict__ dst,
                                const float* __restrict__ w, const float* __restrict__ dinv,
                                const int* __restrict__ rowptr,
                                int* __restrict__ cursor, int* __restrict__ csrc,
                                float* __restrict__ cnorm, int e) {
    int i = blockIdx.x * blockDim.x + threadIdx.x;
    if (i < e) {
        int sN = src[i], dN = dst[i];
        int pos = rowptr[dN] + atomicAdd(&cursor[dN], 1);
        csrc[pos] = sN;
        cnorm[pos] = dinv[sN] * w[i] * dinv[dN];
    }
}
// Transpose gcn_W[l][k][n] -> Wt[l][n][k] bf16 (so GEMM runs A·B^T everywhere)
__global__ void transpose_w_kernel(const float* __restrict__ W, unsigned short* __restrict__ Wt, int total) {
    int i = blockIdx.x * blockDim.x + threadIdx.x;
    if (i < total) {
        int l = i / (D * D);
        int rem = i - l * D * D;
        int k = rem / D;
        int n = rem - k * D;
        Wt[(size_t)l * D * D + (size_t)n * D + k] = f2bu(W[i]);
    }
}

// ---------------- bf16 MFMA GEMM: C = A[M,K](lda) * B[N,K]^T (+bias) -------------
// OUT_MODE 1: bf16 C[M,N] row-major.
// OUT_MODE 2: bf16 gather layout [node][dim][snap]: row gm = node*4+snap.
//             Requires M % 128 == 0 (no store guard).
// 128x128 tile, BK=64, 4 waves 2x2, each wave 64x64 via 4x4 MFMA 16x16x32.
#define GBM 128
#define GBN 128
#define GBK 64
template<int OUT_MODE>
__global__ __launch_bounds__(256) void gemm_bt_bf16_kernel(
    const unsigned short* __restrict__ A, int lda,
    const unsigned short* __restrict__ B,
    const float* __restrict__ bias, unsigned short* __restrict__ C,
    int M, int N, int K)
{
    __shared__ short As[GBM * GBK];
    __shared__ short Bs[GBN * GBK];
    int tid = threadIdx.x;
    int wave = tid >> 6, lane = tid & 63;
    int ln = lane & 15, quad = lane >> 4;
    int wr = wave >> 1, wc = wave & 1;
    int bm = blockIdx.y * GBM, bn = blockIdx.x * GBN;

    v4f acc[4][4];
#pragma unroll
    for (int i = 0; i < 4; ++i)
#pragma unroll
        for (int j = 0; j < 4; ++j)
            acc[i][j] = (v4f)(0.0f);

    int lrow = lane >> 3;          // 0..7 within 8-row segment
    int lcol = (lane & 7) * 8;     // bf16 col offset, 16B chunks

    for (int k0 = 0; k0 < K; k0 += GBK) {
#pragma unroll
        for (int c = 0; c < 4; ++c) {
            int seg = wave * 4 + c;           // 0..15
            int row = seg * 8 + lrow;         // 0..127
            int gm = bm + row; if (gm >= M) gm = M - 1;   // clamp: dup rows, never stored
            __builtin_amdgcn_global_load_lds(
                (const GLOBAL_AS unsigned int*)(A + (size_t)gm * lda + k0 + lcol),
                (LDS_AS unsigned int*)(&As[row * GBK + lcol]), 16, 0, 0);
            int gn = bn + row;                // N % 128 == 0 always here
            __builtin_amdgcn_global_load_lds(
                (const GLOBAL_AS unsigned int*)(B + (size_t)gn * K + k0 + lcol),
                (LDS_AS unsigned int*)(&Bs[row * GBK + lcol]), 16, 0, 0);
        }
        __syncthreads();
#pragma unroll
        for (int ks = 0; ks < 2; ++ks) {
            v8s af[4], bfr[4];
#pragma unroll
            for (int i = 0; i < 4; ++i) {
                int row = wr * 64 + i * 16 + ln;
                af[i] = *(const v8s*)(&As[row * GBK + ks * 32 + quad * 8]);
            }
#pragma unroll
            for (int j = 0; j < 4; ++j) {
                int row = wc * 64 + j * 16 + ln;
                bfr[j] = *(const v8s*)(&Bs[row * GBK + ks * 32 + quad * 8]);
            }
#pragma unroll
            for (int i = 0; i < 4; ++i)
#pragma unroll
                for (int j = 0; j < 4; ++j)
                    acc[i][j] = __builtin_amdgcn_mfma_f32_16x16x32_bf16(af[i], bfr[j], acc[i][j], 0, 0, 0);
        }
        __syncthreads();
    }
    // epilogue: C/D layout col=lane&15, row=quad*4+reg
#pragma unroll
    for (int i = 0; i < 4; ++i) {
        int gmb = bm + wr * 64 + i * 16 + quad * 4;   // base row, multiple of 4
#pragma unroll
        for (int j = 0; j < 4; ++j) {
            int gn = bn + wc * 64 + j * 16 + ln;
            float bv = bias ? bias[gn] : 0.0f;
            if (OUT_MODE == 2) {
                // rows gmb..gmb+3 are the 4 snapshots of node gmb>>2
                ushort4 u;
                u.x = f2bu(acc[i][j][0] + bv);
                u.y = f2bu(acc[i][j][1] + bv);
                u.z = f2bu(acc[i][j][2] + bv);
                u.w = f2bu(acc[i][j][3] + bv);
                int node = gmb >> 2;
                *(ushort4*)(C + ((size_t)node * D + gn) * 4) = u;
            } else {
#pragma unroll
                for (int r = 0; r < 4; ++r) {
                    int gm = gmb + r;
                    if (gm < M) C[(size_t)gm * N + gn] = f2bu(acc[i][j][r] + bv);
                }
            }
        }
    }
}

// ---------------- fp32 GEMM (heads only): C[M,N] = A[M,K]*B[N,K]^T (+bias)(+gelu) --
#define BM 64
#define BN 64
#define BK 16
__global__ __launch_bounds__(256) void gemm_nt_kernel(
    const float* __restrict__ A, const float* __restrict__ B,
    const float* __restrict__ bias, float* __restrict__ C,
    int M, int N, int K, int act)
{
    __shared__ float As[BM][BK + 1];
    __shared__ float Bs[BN][BK + 1];
    int bm = blockIdx.y * BM;
    int bn = blockIdx.x * BN;
    int tid = threadIdx.x;
    int tx = tid & 15;
    int ty = tid >> 4;
    float acc[4][4] = {{0.f}};

    for (int k0 = 0; k0 < K; k0 += BK) {
        int r  = tid >> 2;
        int kk = (tid & 3) * 4;
        int gm = bm + r;
        float4 va = make_float4(0.f, 0.f, 0.f, 0.f);
        if (gm < M) va = *(const float4*)(A + (size_t)gm * K + k0 + kk);
        As[r][kk + 0] = va.x; As[r][kk + 1] = va.y; As[r][kk + 2] = va.z; As[r][kk + 3] = va.w;
        int gn = bn + r;
        float4 vb = make_float4(0.f, 0.f, 0.f, 0.f);
        if (gn < N) vb = *(const float4*)(B + (size_t)gn * K + k0 + kk);
        Bs[r][kk + 0] = vb.x; Bs[r][kk + 1] = vb.y; Bs[r][kk + 2] = vb.z; Bs[r][kk + 3] = vb.w;
        __syncthreads();
#pragma unroll
        for (int kk2 = 0; kk2 < BK; ++kk2) {
            float a[4], b[4];
#pragma unroll
            for (int i = 0; i < 4; ++i) a[i] = As[ty * 4 + i][kk2];
#pragma unroll
            for (int j = 0; j < 4; ++j) b[j] = Bs[tx * 4 + j][kk2];
#pragma unroll
            for (int i = 0; i < 4; ++i)
#pragma unroll
                for (int j = 0; j < 4; ++j)
                    acc[i][j] = fmaf(a[i], b[j], acc[i][j]);
        }
        __syncthreads();
    }
#pragma unroll
    for (int i = 0; i < 4; ++i) {
        int gm = bm + ty * 4 + i;
        if (gm >= M) continue;
#pragma unroll
        for (int j = 0; j < 4; ++j) {
            int gn = bn + tx * 4 + j;
            if (gn >= N) continue;
            float v = acc[i][j];
            if (bias) v += bias[gn];
            if (act == 1) v = gelu_exact(v);
            C[(size_t)gm * N + gn] = v;
        }
    }
}

// ------- GCN aggregate (4 snapshots) + bias + LayerNorm + ReLU, one block/node ----
// hWb: [node][dim][snap] bf16 (ushort4 per (node,dim)); out: [node*4+s][dim] bf16
__global__ __launch_bounds__(256) void gcn_agg_ln_relu4_kernel(
    const unsigned short* __restrict__ hWb, const int* __restrict__ rowptr,
    const int* __restrict__ csrc, const float* __restrict__ cnorm,
    const float* __restrict__ selfnorm,
    const float* __restrict__ gcn_b, const float* __restrict__ ln_g,
    const float* __restrict__ ln_b, unsigned short* __restrict__ out)
{
    int i = blockIdx.x;
    int d = threadIdx.x;
    const ushort4* tbl = (const ushort4*)hWb;

    float a0, a1, a2, a3;
    {
        ushort4 v = tbl[(size_t)i * D + d];
        float w = selfnorm[i];
        a0 = w * b2f(v.x); a1 = w * b2f(v.y); a2 = w * b2f(v.z); a3 = w * b2f(v.w);
    }
    int beg = rowptr[i], end = rowptr[i + 1];
    int p = beg;
    for (; p + 1 < end; p += 2) {
        int sA = csrc[p], sB = csrc[p + 1];
        float wA = cnorm[p], wB = cnorm[p + 1];
        ushort4 uA = tbl[(size_t)sA * D + d];
        ushort4 uB = tbl[(size_t)sB * D + d];
        a0 = fmaf(wA, b2f(uA.x), a0); a1 = fmaf(wA, b2f(uA.y), a1);
        a2 = fmaf(wA, b2f(uA.z), a2); a3 = fmaf(wA, b2f(uA.w), a3);
        a0 = fmaf(wB, b2f(uB.x), a0); a1 = fmaf(wB, b2f(uB.y), a1);
        a2 = fmaf(wB, b2f(uB.z), a2); a3 = fmaf(wB, b2f(uB.w), a3);
    }
    if (p < end) {
        int sA = csrc[p]; float wA = cnorm[p];
        ushort4 uA = tbl[(size_t)sA * D + d];
        a0 = fmaf(wA, b2f(uA.x), a0); a1 = fmaf(wA, b2f(uA.y), a1);
        a2 = fmaf(wA, b2f(uA.z), a2); a3 = fmaf(wA, b2f(uA.w), a3);
    }
    float bb = gcn_b[d];
    a0 += bb; a1 += bb; a2 += bb; a3 += bb;

    __shared__ float4 s1[256];
    __shared__ float4 s2[256];
    s1[d] = make_float4(a0, a1, a2, a3);
    s2[d] = make_float4(a0 * a0, a1 * a1, a2 * a2, a3 * a3);
    __syncthreads();
    for (int st = 128; st > 0; st >>= 1) {
        if (d < st) {
            float4 x1 = s1[d], y1 = s1[d + st];
            float4 x2 = s2[d], y2 = s2[d + st];
            s1[d] = make_float4(x1.x + y1.x, x1.y + y1.y, x1.z + y1.z, x1.w + y1.w);
            s2[d] = make_float4(x2.x + y2.x, x2.y + y2.y, x2.z + y2.z, x2.w + y2.w);
        }
        __syncthreads();
    }
    float4 sm = s1[0], sq = s2[0];
    const float inv = 1.0f / D;
    float m0 = sm.x * inv, m1 = sm.y * inv, m2 = sm.z * inv, m3 = sm.w * inv;
    float r0 = rsqrtf(sq.x * inv - m0 * m0 + 1e-5f);
    float r1 = rsqrtf(sq.y * inv - m1 * m1 + 1e-5f);
    float r2 = rsqrtf(sq.z * inv - m2 * m2 + 1e-5f);
    float r3 = rsqrtf(sq.w * inv - m3 * m3 + 1e-5f);
    float g = ln_g[d], lb = ln_b[d];
    size_t ob = (size_t)(i << 2) * D + d;
    out[ob + 0 * D] = f2bu(fmaxf((a0 - m0) * r0 * g + lb, 0.0f));
    out[ob + 1 * D] = f2bu(fmaxf((a1 - m1) * r1 * g + lb, 0.0f));
    out[ob + 2 * D] = f2bu(fmaxf((a2 - m2) * r2 * g + lb, 0.0f));
    out[ob + 3 * D] = f2bu(fmaxf((a3 - m3) * r3 * g + lb, 0.0f));
}

// ---------------- GRU gate elementwise (bf16 gi/gh): h f32 + bf16 copy ------------
__global__ void gru_gates_kernel(const unsigned short* __restrict__ gi,
                                 const unsigned short* __restrict__ gh,
                                 float* __restrict__ h, unsigned short* __restrict__ hb, int n) {
    int idx = blockIdx.x * blockDim.x + threadIdx.x;
    if (idx >= n) return;
    int i = idx >> 8;       // / D
    int d = idx & 255;      // % D
    const unsigned short* gir = gi + (size_t)i * 3 * D;
    const unsigned short* ghr = gh + (size_t)i * 3 * D;
    float ir = b2f(gir[d]), iz = b2f(gir[D + d]), ig = b2f(gir[2 * D + d]);
    float hr = b2f(ghr[d]), hz = b2f(ghr[D + d]), hg = b2f(ghr[2 * D + d]);
    float r = 1.0f / (1.0f + expf(-(ir + hr)));
    float z = 1.0f / (1.0f + expf(-(iz + hz)));
    float nn = tanhf(ig + r * hg);
    float hv = (1.0f - z) * nn + z * h[idx];
    h[idx] = hv;
    hb[idx] = f2bu(hv);
}

// ---------------- small output head: C[M,5] = A[M,K] * W[5,K]^T + b ----------------
__global__ void head5_kernel(const float* __restrict__ A, const float* __restrict__ W,
                             const float* __restrict__ b, float* __restrict__ C,
                             int M, int K) {
    int idx = blockIdx.x * blockDim.x + threadIdx.x;
    if (idx >= M * H) return;
    int m = idx / H;
    int h = idx - m * H;
    const float* ar = A + (size_t)m * K;
    const float* wr = W + (size_t)h * K;
    float s = 0.0f;
    for (int k = 0; k < K; ++k) s = fmaf(ar[k], wr[k], s);
    C[idx] = s + b[h];
}

extern "C" void kernel_launch(void* const* d_in, const int* in_sizes, int n_in,
                              void* d_out, int out_size, void* d_ws, size_t ws_size,
                              hipStream_t stream)
{
    const float* x     = (const float*)d_in[0];
    const int*   esrc  = (const int*)d_in[1];
    const int*   edst  = (const int*)d_in[2];
    const float* ew    = (const float*)d_in[3];
    const float* gcn_W = (const float*)d_in[4];
    const float* gcn_b = (const float*)d_in[5];
    const float* ln_g  = (const float*)d_in[6];
    const float* ln_b  = (const float*)d_in[7];
    const float* Wih   = (const float*)d_in[8];
    const float* Whh   = (const float*)d_in[9];
    const float* bih   = (const float*)d_in[10];
    const float* bhh   = (const float*)d_in[11];
    const float* fc1W  = (const float*)d_in[12];
    const float* fc1b  = (const float*)d_in[13];
    const float* fc2W  = (const float*)d_in[14];
    const float* fc2b  = (const float*)d_in[15];
    const float* fc3W  = (const float*)d_in[16];
    const float* fc3b  = (const float*)d_in[17];
    const float* dh1W  = (const float*)d_in[18];
    const float* dh1b  = (const float*)d_in[19];
    const float* dh2W  = (const float*)d_in[20];
    const float* dh2b  = (const float*)d_in[21];

    float* out = (float*)d_out;   // [Nn*H forecast][Nn*H direction]

    // workspace carve-out (aligned to 256B)
    char* p = (char*)d_ws;
    auto alloc = [&](size_t bytes) -> void* {
        void* r = (void*)p;
        p += (bytes + 255) & ~(size_t)255;
        return r;
    };
    float* deg      = (float*)alloc((size_t)Nn * 4);
    float* dinv     = (float*)alloc((size_t)Nn * 4);
    float* selfnorm = (float*)alloc((size_t)Nn * 4);
    int*   rowptr   = (int*)alloc((size_t)(Nn + 1) * 4);
    int*   cnt      = (int*)alloc((size_t)Nn * 4);
    int*   csrc     = (int*)alloc((size_t)E * 4);
    float* cnorm    = (float*)alloc((size_t)E * 4);
    unsigned short* Wtb  = (unsigned short*)alloc((size_t)L * D * D * 2);
    unsigned short* Wihb = (unsigned short*)alloc((size_t)3 * D * D * 2);
    unsigned short* Whhb = (unsigned short*)alloc((size_t)3 * D * D * 2);
    unsigned short* bufA = (unsigned short*)alloc((size_t)Nn * S * D * 2);     // 41MB A-layout
    unsigned short* hWb  = (unsigned short*)alloc((size_t)Nn * D * S * 2);     // 41MB gather layout
    unsigned short* gh_bf = (unsigned short*)alloc((size_t)Nn * 3 * D * 2);    // 30.7MB
    float* hgru     = (float*)alloc((size_t)Nn * D * 4);                       // 20.5MB
    unsigned short* hgru_bf = (unsigned short*)alloc((size_t)Nn * D * 2);      // 10.2MB
    // aliases: gi_bf fits in hWb (free after GCN); head scratch in gh_bf / hWb
    unsigned short* gi_bf = hWb;
    float* f1 = (float*)gh_bf;                       // [Nn,128] 10.2MB
    float* f2 = (float*)(gh_bf + (size_t)Nn * 256);  // [Nn,64]  5.1MB (offset 10.2MB)
    float* d1 = (float*)hWb;                         // [Nn,64]

    auto cdiv = [](int a, int b) { return (a + b - 1) / b; };

    // ---- graph preprocessing ----
    zero_i_kernel<<<cdiv(Nn, 256), 256, 0, stream>>>(cnt, Nn);
    deg_init_kernel<<<cdiv(Nn, 256), 256, 0, stream>>>(deg, Nn);
    deg_edge_kernel<<<cdiv(E, 256), 256, 0, stream>>>(edst, ew, deg, E);
    dinv_kernel<<<cdiv(Nn, 256), 256, 0, stream>>>(deg, dinv, selfnorm, Nn);
    hist_kernel<<<cdiv(E, 256), 256, 0, stream>>>(edst, cnt, E);
    scan_rowptr_kernel<<<1, 256, 0, stream>>>(cnt, rowptr, Nn);
    zero_i_kernel<<<cdiv(Nn, 256), 256, 0, stream>>>(cnt, Nn);
    csr_fill_kernel<<<cdiv(E, 256), 256, 0, stream>>>(esrc, edst, ew, dinv, rowptr, cnt, csrc, cnorm, E);
    transpose_w_kernel<<<cdiv(L * D * D, 256), 256, 0, stream>>>(gcn_W, Wtb, L * D * D);
    f2b_kernel<<<cdiv(3 * D * D, 256), 256, 0, stream>>>(Wih, Wihb, 3 * D * D);
    f2b_kernel<<<cdiv(3 * D * D, 256), 256, 0, stream>>>(Whh, Whhb, 3 * D * D);
    zero_f_kernel<<<cdiv(Nn * D, 256), 256, 0, stream>>>(hgru, Nn * D);
    zero_b_kernel<<<cdiv(Nn * D, 256), 256, 0, stream>>>(hgru_bf, Nn * D);
    x_to_blocked_kernel<<<Nn * S, 256, 0, stream>>>(x, bufA);

    // ---- batched GCN stack: all 4 snapshots at once ----
    for (int l = 0; l < L; ++l) {
        dim3 g1(D / GBN, (Nn * S) / GBM);   // (2, 625)
        gemm_bt_bf16_kernel<2><<<g1, 256, 0, stream>>>(
            bufA, D, Wtb + (size_t)l * D * D, nullptr, hWb, Nn * S, D, D);
        gcn_agg_ln_relu4_kernel<<<Nn, 256, 0, stream>>>(
            hWb, rowptr, csrc, cnorm, selfnorm,
            gcn_b + (size_t)l * D, ln_g + (size_t)l * D, ln_b + (size_t)l * D, bufA);
    }

    // ---- GRU loop (sequential over snapshots) ----
    for (int s = 0; s < S; ++s) {
        dim3 g2((3 * D) / GBN, cdiv(Nn, GBM));   // (6, 157)
        // gi = feats_s @ Wih^T + bih  (A rows strided: row n at bufA + (n*S+s)*D)
        gemm_bt_bf16_kernel<1><<<g2, 256, 0, stream>>>(
            bufA + (size_t)s * D, S * D, Wihb, bih, gi_bf, Nn, 3 * D, D);
        gemm_bt_bf16_kernel<1><<<g2, 256, 0, stream>>>(
            hgru_bf, D, Whhb, bhh, gh_bf, Nn, 3 * D, D);
        gru_gates_kernel<<<cdiv(Nn * D, 256), 256, 0, stream>>>(gi_bf, gh_bf, hgru, hgru_bf, Nn * D);
    }

    // ---- heads (f32) ----
    auto gemm_f = [&](const float* A, const float* B, const float* bias, float* C,
                      int M, int Ncols, int K, int act) {
        dim3 g(cdiv(Ncols, BN), cdiv(M, BM));
        gemm_nt_kernel<<<g, 256, 0, stream>>>(A, B, bias, C, M, Ncols, K, act);
    };
    gemm_f(hgru, fc1W, fc1b, f1, Nn, 128, 256, 1);     // gelu
    gemm_f(f1,   fc2W, fc2b, f2, Nn, 64, 128, 1);      // gelu
    head5_kernel<<<cdiv(Nn * H, 256), 256, 0, stream>>>(f2, fc3W, fc3b, out, Nn, 64);
    gemm_f(hgru, dh1W, dh1b, d1, Nn, 64, 256, 1);      // gelu
    head5_kernel<<<cdiv(Nn * H, 256), 256, 0, stream>>>(d1, dh2W, dh2b, out + (size_t)Nn * H, Nn, 64);
}

// Round 4
// 1073.865 us; speedup vs baseline: 3.4385x; 1.0851x over previous
//
#include <hip/hip_runtime.h>
#include <hip/hip_bf16.h>

// Problem constants (from reference)
constexpr int Nn = 20000;   // nodes
constexpr int D  = 256;     // feature dim
constexpr int S  = 4;       // snapshots
constexpr int E  = 320000;  // edges
constexpr int H  = 5;       // horizon
constexpr int L  = 3;       // GCN layers

using bf16 = __hip_bfloat16;
typedef __attribute__((ext_vector_type(8))) short v8s;   // 8 bf16 = 4 VGPRs
typedef __attribute__((ext_vector_type(4))) float v4f;   // MFMA acc

#define GLOBAL_AS __attribute__((address_space(1)))
#define LDS_AS    __attribute__((address_space(3)))

__device__ __forceinline__ float gelu_exact(float x) {
    return 0.5f * x * (1.0f + erff(x * 0.70710678118654752440f));
}
__device__ __forceinline__ unsigned short f2bu(float f) {
    bf16 h = __float2bfloat16(f);
    return *reinterpret_cast<unsigned short*>(&h);
}
__device__ __forceinline__ float b2f(unsigned short u) {
    unsigned int v = (unsigned int)u << 16;
    return __uint_as_float(v);
}

// ---------------- fused preprocessing kernels ----------------
// deg=1 (self loop), cnt=0
__global__ void init_deg_cnt_kernel(float* deg, int* cnt, int n) {
    int i = blockIdx.x * blockDim.x + threadIdx.x;
    if (i < n) { deg[i] = 1.0f; cnt[i] = 0; }
}
// deg += w (by dst), cnt += 1 (by dst)
__global__ void deg_hist_kernel(const int* __restrict__ dst, const float* __restrict__ w,
                                float* __restrict__ deg, int* __restrict__ cnt, int e) {
    int i = blockIdx.x * blockDim.x + threadIdx.x;
    if (i < e) {
        int d = dst[i];
        atomicAdd(&deg[d], w[i]);
        atomicAdd(&cnt[d], 1);
    }
}
__global__ void dinv_kernel(const float* __restrict__ deg, float* __restrict__ dinv,
                            float* __restrict__ selfnorm, int n) {
    int i = blockIdx.x * blockDim.x + threadIdx.x;
    if (i < n) {
        float dg = deg[i];
        float dv = dg > 0.0f ? rsqrtf(fmaxf(dg, 1e-5f)) : 0.0f;
        dinv[i] = dv;
        selfnorm[i] = dv * dv;
    }
}
// Single-block exclusive scan over cnt -> rowptr; zeroes cnt (reused as cursor)
__global__ __launch_bounds__(256) void scan_rowptr_kernel(int* __restrict__ cnt,
                                                          int* __restrict__ rowptr, int n) {
    __shared__ int ssum[256];
    int t = threadIdx.x;
    int chunk = (n + 255) / 256;
    int start = t * chunk;
    int end = start + chunk; if (end > n) end = n;
    int s = 0;
    for (int i = start; i < end; ++i) s += cnt[i];
    ssum[t] = s;
    __syncthreads();
    if (t == 0) {
        int acc = 0;
        for (int i = 0; i < 256; ++i) { int v = ssum[i]; ssum[i] = acc; acc += v; }
        rowptr[n] = acc;
    }
    __syncthreads();
    int acc = ssum[t];
    for (int i = start; i < end; ++i) {
        rowptr[i] = acc; acc += cnt[i]; cnt[i] = 0;
    }
}
// fill CSR with inline norm = dinv[src]*w*dinv[dst]
__global__ void csr_fill_kernel(const int* __restrict__ src, const int* __restrict__ dst,
                                const float* __restrict__ w, const float* __restrict__ dinv,
                                const int* __restrict__ rowptr,
                                int* __restrict__ cursor, int* __restrict__ csrc,
                                float* __restrict__ cnorm, int e) {
    int i = blockIdx.x * blockDim.x + threadIdx.x;
    if (i < e) {
        int sN = src[i], dN = dst[i];
        int pos = rowptr[dN] + atomicAdd(&cursor[dN], 1);
        csrc[pos] = sN;
        cnorm[pos] = dinv[sN] * w[i] * dinv[dN];
    }
}
// All weight conversions in one kernel.
// seg0: gcn_W [L,D,D] -> Wtb transposed [l][n][k] bf16
// seg1: Wih -> bf16 ; seg2: Whh -> bf16 ; seg3: fc1W ; seg4: fc2W ; seg5: dh1W
constexpr int CW0 = L * D * D;          // 196608
constexpr int CW1 = CW0 + 3 * D * D;    // +196608
constexpr int CW2 = CW1 + 3 * D * D;
constexpr int CW3 = CW2 + 128 * 256;
constexpr int CW4 = CW3 + 64 * 128;
constexpr int CW5 = CW4 + 64 * 256;
__global__ void convert_weights_kernel(
    const float* __restrict__ gcn_W, const float* __restrict__ Wih,
    const float* __restrict__ Whh, const float* __restrict__ fc1W,
    const float* __restrict__ fc2W, const float* __restrict__ dh1W,
    unsigned short* __restrict__ Wtb, unsigned short* __restrict__ Wihb,
    unsigned short* __restrict__ Whhb, unsigned short* __restrict__ fc1Wb,
    unsigned short* __restrict__ fc2Wb, unsigned short* __restrict__ dh1Wb)
{
    int i = blockIdx.x * blockDim.x + threadIdx.x;
    if (i < CW0) {
        int l = i / (D * D);
        int rem = i - l * D * D;
        int k = rem / D;
        int n = rem - k * D;
        Wtb[(size_t)l * D * D + (size_t)n * D + k] = f2bu(gcn_W[i]);
    } else if (i < CW1) { int j = i - CW0; Wihb[j]  = f2bu(Wih[j]);  }
    else if (i < CW2)   { int j = i - CW1; Whhb[j]  = f2bu(Whh[j]);  }
    else if (i < CW3)   { int j = i - CW2; fc1Wb[j] = f2bu(fc1W[j]); }
    else if (i < CW4)   { int j = i - CW3; fc2Wb[j] = f2bu(fc2W[j]); }
    else if (i < CW5)   { int j = i - CW4; dh1Wb[j] = f2bu(dh1W[j]); }
}
// hgru = 0.f, hgru_bf = 0
__global__ void init_h_kernel(float* h, unsigned short* hb, int n) {
    int i = blockIdx.x * blockDim.x + threadIdx.x;
    if (i < n) { h[i] = 0.0f; hb[i] = 0; }
}
// x [S,N,D] f32 -> blocked [n*S+s][D] bf16, vectorized x4
__global__ __launch_bounds__(256) void x_to_blocked_kernel(const float* __restrict__ x,
                                                           unsigned short* __restrict__ out) {
    int tid = blockIdx.x * blockDim.x + threadIdx.x;   // over Nn*S*D/4
    if (tid >= Nn * S * (D / 4)) return;
    int row = tid >> 6;           // / 64 : row = s*Nn + n
    int r64 = tid & 63;
    int s = row / Nn;
    int n = row - s * Nn;
    float4 v = ((const float4*)x)[(size_t)row * 64 + r64];
    ushort4 u;
    u.x = f2bu(v.x); u.y = f2bu(v.y); u.z = f2bu(v.z); u.w = f2bu(v.w);
    ((ushort4*)out)[((size_t)(n * 4 + s)) * 64 + r64] = u;
}

// ---------------- bf16 MFMA GEMM: C = A[M,K](lda) * B[N,K]^T (+bias) -------------
// OUT_MODE 1: bf16 C[M,N] row-major (store-guarded on M and N; gelu if ACT).
// OUT_MODE 2: bf16 gather layout [node][dim][snap]: row gm = node*4+snap (M%128==0).
// 128x128 tile, BK=64, 4 waves 2x2, each wave 64x64 via 4x4 MFMA 16x16x32.
#define GBM 128
#define GBN 128
#define GBK 64
template<int OUT_MODE, int ACT>
__global__ __launch_bounds__(256) void gemm_bt_bf16_kernel(
    const unsigned short* __restrict__ A, int lda,
    const unsigned short* __restrict__ B,
    const float* __restrict__ bias, unsigned short* __restrict__ C,
    int M, int N, int K)
{
    __shared__ short As[GBM * GBK];
    __shared__ short Bs[GBN * GBK];
    int tid = threadIdx.x;
    int wave = tid >> 6, lane = tid & 63;
    int ln = lane & 15, quad = lane >> 4;
    int wr = wave >> 1, wc = wave & 1;
    int bm = blockIdx.y * GBM, bn = blockIdx.x * GBN;

    v4f acc[4][4];
#pragma unroll
    for (int i = 0; i < 4; ++i)
#pragma unroll
        for (int j = 0; j < 4; ++j)
            acc[i][j] = (v4f)(0.0f);

    int lrow = lane >> 3;          // 0..7 within 8-row segment
    int lcol = (lane & 7) * 8;     // bf16 col offset, 16B chunks

    for (int k0 = 0; k0 < K; k0 += GBK) {
#pragma unroll
        for (int c = 0; c < 4; ++c) {
            int seg = wave * 4 + c;           // 0..15
            int row = seg * 8 + lrow;         // 0..127
            int gm = bm + row; if (gm >= M) gm = M - 1;   // clamp: dup rows, never stored
            __builtin_amdgcn_global_load_lds(
                (const GLOBAL_AS unsigned int*)(A + (size_t)gm * lda + k0 + lcol),
                (LDS_AS unsigned int*)(&As[row * GBK + lcol]), 16, 0, 0);
            int gn = bn + row; if (gn >= N) gn = N - 1;   // clamp for N=64/128 heads
            __builtin_amdgcn_global_load_lds(
                (const GLOBAL_AS unsigned int*)(B + (size_t)gn * K + k0 + lcol),
                (LDS_AS unsigned int*)(&Bs[row * GBK + lcol]), 16, 0, 0);
        }
        __syncthreads();
#pragma unroll
        for (int ks = 0; ks < 2; ++ks) {
            v8s af[4], bfr[4];
#pragma unroll
            for (int i = 0; i < 4; ++i) {
                int row = wr * 64 + i * 16 + ln;
                af[i] = *(const v8s*)(&As[row * GBK + ks * 32 + quad * 8]);
            }
#pragma unroll
            for (int j = 0; j < 4; ++j) {
                int row = wc * 64 + j * 16 + ln;
                bfr[j] = *(const v8s*)(&Bs[row * GBK + ks * 32 + quad * 8]);
            }
#pragma unroll
            for (int i = 0; i < 4; ++i)
#pragma unroll
                for (int j = 0; j < 4; ++j)
                    acc[i][j] = __builtin_amdgcn_mfma_f32_16x16x32_bf16(af[i], bfr[j], acc[i][j], 0, 0, 0);
        }
        __syncthreads();
    }
    // epilogue: C/D layout col=lane&15, row=quad*4+reg
#pragma unroll
    for (int i = 0; i < 4; ++i) {
        int gmb = bm + wr * 64 + i * 16 + quad * 4;   // base row, multiple of 4
#pragma unroll
        for (int j = 0; j < 4; ++j) {
            int gn = bn + wc * 64 + j * 16 + ln;
            float bv = (bias && gn < N) ? bias[gn] : 0.0f;
            if (OUT_MODE == 2) {
                // rows gmb..gmb+3 are the 4 snapshots of node gmb>>2
                ushort4 u;
                u.x = f2bu(acc[i][j][0] + bv);
                u.y = f2bu(acc[i][j][1] + bv);
                u.z = f2bu(acc[i][j][2] + bv);
                u.w = f2bu(acc[i][j][3] + bv);
                int node = gmb >> 2;
                *(ushort4*)(C + ((size_t)node * D + gn) * 4) = u;
            } else {
                if (gn < N) {
#pragma unroll
                    for (int r = 0; r < 4; ++r) {
                        int gm = gmb + r;
                        if (gm < M) {
                            float v = acc[i][j][r] + bv;
                            if (ACT == 1) v = gelu_exact(v);
                            C[(size_t)gm * N + gn] = f2bu(v);
                        }
                    }
                }
            }
        }
    }
}

// ------- GCN aggregate (4 snapshots) + bias + LayerNorm + ReLU, one WAVE/node ----
// hWb: [node][dim][snap] bf16 (ushort4 per (node,dim)); out: [node*4+s][dim] bf16
// Block = 256 = 4 waves, wave w handles node blockIdx.x*4+w; lane owns dims
// lane, lane+64, lane+128, lane+192. LN reduction via wave shuffles (no LDS).
__global__ __launch_bounds__(256) void gcn_agg_ln_relu4_kernel(
    const unsigned short* __restrict__ hWb, const int* __restrict__ rowptr,
    const int* __restrict__ csrc, const float* __restrict__ cnorm,
    const float* __restrict__ selfnorm,
    const float* __restrict__ gcn_b, const float* __restrict__ ln_g,
    const float* __restrict__ ln_b, unsigned short* __restrict__ out)
{
    int wave = threadIdx.x >> 6, lane = threadIdx.x & 63;
    int i = blockIdx.x * 4 + wave;
    const ushort4* tbl = (const ushort4*)hWb;

    float acc[4][4];   // [q dim-seg][s snap]
    {
        float w = selfnorm[i];
#pragma unroll
        for (int q = 0; q < 4; ++q) {
            ushort4 u = tbl[(size_t)i * D + lane + q * 64];
            acc[q][0] = w * b2f(u.x); acc[q][1] = w * b2f(u.y);
            acc[q][2] = w * b2f(u.z); acc[q][3] = w * b2f(u.w);
        }
    }
    int beg = rowptr[i], end = rowptr[i + 1];
    int p = beg;
    for (; p + 1 < end; p += 2) {
        int sA = csrc[p], sB = csrc[p + 1];
        float wA = cnorm[p], wB = cnorm[p + 1];
        ushort4 uA[4], uB[4];
#pragma unroll
        for (int q = 0; q < 4; ++q) uA[q] = tbl[(size_t)sA * D + lane + q * 64];
#pragma unroll
        for (int q = 0; q < 4; ++q) uB[q] = tbl[(size_t)sB * D + lane + q * 64];
#pragma unroll
        for (int q = 0; q < 4; ++q) {
            acc[q][0] = fmaf(wA, b2f(uA[q].x), acc[q][0]);
            acc[q][1] = fmaf(wA, b2f(uA[q].y), acc[q][1]);
            acc[q][2] = fmaf(wA, b2f(uA[q].z), acc[q][2]);
            acc[q][3] = fmaf(wA, b2f(uA[q].w), acc[q][3]);
            acc[q][0] = fmaf(wB, b2f(uB[q].x), acc[q][0]);
            acc[q][1] = fmaf(wB, b2f(uB[q].y), acc[q][1]);
            acc[q][2] = fmaf(wB, b2f(uB[q].z), acc[q][2]);
            acc[q][3] = fmaf(wB, b2f(uB[q].w), acc[q][3]);
        }
    }
    if (p < end) {
        int sA = csrc[p]; float wA = cnorm[p];
#pragma unroll
        for (int q = 0; q < 4; ++q) {
            ushort4 u = tbl[(size_t)sA * D + lane + q * 64];
            acc[q][0] = fmaf(wA, b2f(u.x), acc[q][0]);
            acc[q][1] = fmaf(wA, b2f(u.y), acc[q][1]);
            acc[q][2] = fmaf(wA, b2f(u.z), acc[q][2]);
            acc[q][3] = fmaf(wA, b2f(u.w), acc[q][3]);
        }
    }
#pragma unroll
    for (int q = 0; q < 4; ++q) {
        float bb = gcn_b[lane + q * 64];
        acc[q][0] += bb; acc[q][1] += bb; acc[q][2] += bb; acc[q][3] += bb;
    }
    // LN sums per snapshot over 256 dims
    float s1[4], s2[4];
#pragma unroll
    for (int s = 0; s < 4; ++s) {
        s1[s] = acc[0][s] + acc[1][s] + acc[2][s] + acc[3][s];
        s2[s] = acc[0][s] * acc[0][s] + acc[1][s] * acc[1][s]
              + acc[2][s] * acc[2][s] + acc[3][s] * acc[3][s];
    }
#pragma unroll
    for (int off = 32; off > 0; off >>= 1) {
#pragma unroll
        for (int s = 0; s < 4; ++s) {
            s1[s] += __shfl_xor(s1[s], off);
            s2[s] += __shfl_xor(s2[s], off);
        }
    }
    const float inv = 1.0f / D;
    float m[4], rr[4];
#pragma unroll
    for (int s = 0; s < 4; ++s) {
        m[s] = s1[s] * inv;
        rr[s] = rsqrtf(s2[s] * inv - m[s] * m[s] + 1e-5f);
    }
    size_t ob = (size_t)(i << 2) * D;
#pragma unroll
    for (int q = 0; q < 4; ++q) {
        int d = lane + q * 64;
        float g = ln_g[d], lb = ln_b[d];
#pragma unroll
        for (int s = 0; s < 4; ++s) {
            float y = (acc[q][s] - m[s]) * rr[s] * g + lb;
            out[ob + (size_t)s * D + d] = f2bu(fmaxf(y, 0.0f));
        }
    }
}

// ---------------- GRU gate elementwise, vectorized x4 ----------------
__global__ void gru_gates_kernel(const unsigned short* __restrict__ gi,
                                 const unsigned short* __restrict__ gh,
                                 float* __restrict__ h, unsigned short* __restrict__ hb) {
    int idx = blockIdx.x * blockDim.x + threadIdx.x;   // over Nn*D/4
    if (idx >= Nn * (D / 4)) return;
    int i = idx >> 6;         // node
    int t = idx & 63;         // dim4 index
    const ushort4* gir = (const ushort4*)(gi + (size_t)i * 3 * D);
    const ushort4* ghr = (const ushort4*)(gh + (size_t)i * 3 * D);
    ushort4 uir = gir[t], uiz = gir[64 + t], uig = gir[128 + t];
    ushort4 uhr = ghr[t], uhz = ghr[64 + t], uhg = ghr[128 + t];
    float4 hv = ((const float4*)h)[(size_t)i * 64 + t];
    float o[4];
    {
        float ir[4] = {b2f(uir.x), b2f(uir.y), b2f(uir.z), b2f(uir.w)};
        float iz[4] = {b2f(uiz.x), b2f(uiz.y), b2f(uiz.z), b2f(uiz.w)};
        float ig[4] = {b2f(uig.x), b2f(uig.y), b2f(uig.z), b2f(uig.w)};
        float hr[4] = {b2f(uhr.x), b2f(uhr.y), b2f(uhr.z), b2f(uhr.w)};
        float hz[4] = {b2f(uhz.x), b2f(uhz.y), b2f(uhz.z), b2f(uhz.w)};
        float hg[4] = {b2f(uhg.x), b2f(uhg.y), b2f(uhg.z), b2f(uhg.w)};
        float hh[4] = {hv.x, hv.y, hv.z, hv.w};
#pragma unroll
        for (int k = 0; k < 4; ++k) {
            float r = 1.0f / (1.0f + expf(-(ir[k] + hr[k])));
            float z = 1.0f / (1.0f + expf(-(iz[k] + hz[k])));
            float nn = tanhf(ig[k] + r * hg[k]);
            o[k] = (1.0f - z) * nn + z * hh[k];
        }
    }
    ((float4*)h)[(size_t)i * 64 + t] = make_float4(o[0], o[1], o[2], o[3]);
    ushort4 ub;
    ub.x = f2bu(o[0]); ub.y = f2bu(o[1]); ub.z = f2bu(o[2]); ub.w = f2bu(o[3]);
    ((ushort4*)hb)[(size_t)i * 64 + t] = ub;
}

// ---------------- small output head: C[M,5] = A_bf16[M,K] * W[5,K]^T + b ----------
__global__ void head5_bf_kernel(const unsigned short* __restrict__ A,
                                const float* __restrict__ W,
                                const float* __restrict__ b, float* __restrict__ C,
                                int M, int K) {
    int idx = blockIdx.x * blockDim.x + threadIdx.x;
    if (idx >= M * H) return;
    int m = idx / H;
    int h = idx - m * H;
    const ushort4* ar = (const ushort4*)(A + (size_t)m * K);
    const float* wr = W + (size_t)h * K;
    float s = 0.0f;
    for (int k4 = 0; k4 < K / 4; ++k4) {
        ushort4 u = ar[k4];
        s = fmaf(b2f(u.x), wr[4 * k4 + 0], s);
        s = fmaf(b2f(u.y), wr[4 * k4 + 1], s);
        s = fmaf(b2f(u.z), wr[4 * k4 + 2], s);
        s = fmaf(b2f(u.w), wr[4 * k4 + 3], s);
    }
    C[idx] = s + b[h];
}

extern "C" void kernel_launch(void* const* d_in, const int* in_sizes, int n_in,
                              void* d_out, int out_size, void* d_ws, size_t ws_size,
                              hipStream_t stream)
{
    const float* x     = (const float*)d_in[0];
    const int*   esrc  = (const int*)d_in[1];
    const int*   edst  = (const int*)d_in[2];
    const float* ew    = (const float*)d_in[3];
    const float* gcn_W = (const float*)d_in[4];
    const float* gcn_b = (const float*)d_in[5];
    const float* ln_g  = (const float*)d_in[6];
    const float* ln_b  = (const float*)d_in[7];
    const float* Wih   = (const float*)d_in[8];
    const float* Whh   = (const float*)d_in[9];
    const float* bih   = (const float*)d_in[10];
    const float* bhh   = (const float*)d_in[11];
    const float* fc1W  = (const float*)d_in[12];
    const float* fc1b  = (const float*)d_in[13];
    const float* fc2W  = (const float*)d_in[14];
    const float* fc2b  = (const float*)d_in[15];
    const float* fc3W  = (const float*)d_in[16];
    const float* fc3b  = (const float*)d_in[17];
    const float* dh1W  = (const float*)d_in[18];
    const float* dh1b  = (const float*)d_in[19];
    const float* dh2W  = (const float*)d_in[20];
    const float* dh2b  = (const float*)d_in[21];

    float* out = (float*)d_out;   // [Nn*H forecast][Nn*H direction]

    // workspace carve-out (aligned to 256B); total ~148 MB
    char* p = (char*)d_ws;
    auto alloc = [&](size_t bytes) -> void* {
        void* r = (void*)p;
        p += (bytes + 255) & ~(size_t)255;
        return r;
    };
    float* deg      = (float*)alloc((size_t)Nn * 4);
    float* dinv     = (float*)alloc((size_t)Nn * 4);
    float* selfnorm = (float*)alloc((size_t)Nn * 4);
    int*   rowptr   = (int*)alloc((size_t)(Nn + 1) * 4);
    int*   cnt      = (int*)alloc((size_t)Nn * 4);
    int*   csrc     = (int*)alloc((size_t)E * 4);
    float* cnorm    = (float*)alloc((size_t)E * 4);
    unsigned short* Wtb   = (unsigned short*)alloc((size_t)L * D * D * 2);
    unsigned short* Wihb  = (unsigned short*)alloc((size_t)3 * D * D * 2);
    unsigned short* Whhb  = (unsigned short*)alloc((size_t)3 * D * D * 2);
    unsigned short* fc1Wb = (unsigned short*)alloc((size_t)128 * 256 * 2);
    unsigned short* fc2Wb = (unsigned short*)alloc((size_t)64 * 128 * 2);
    unsigned short* dh1Wb = (unsigned short*)alloc((size_t)64 * 256 * 2);
    unsigned short* bufA  = (unsigned short*)alloc((size_t)Nn * S * D * 2);    // 41MB A-layout
    unsigned short* hWb   = (unsigned short*)alloc((size_t)Nn * D * S * 2);    // 41MB gather layout
    unsigned short* gh_bf = (unsigned short*)alloc((size_t)Nn * 3 * D * 2);    // 30.7MB
    float* hgru     = (float*)alloc((size_t)Nn * D * 4);                       // 20.5MB
    unsigned short* hgru_bf = (unsigned short*)alloc((size_t)Nn * D * 2);      // 10.2MB
    // aliases: gi_bf in hWb (free after GCN); head scratch in gh_bf / hWb
    unsigned short* gi_bf = hWb;
    unsigned short* f1 = gh_bf;                       // [Nn,128] bf16
    unsigned short* f2 = gh_bf + (size_t)Nn * 128;    // [Nn,64]  bf16
    unsigned short* d1 = hWb;                         // [Nn,64]  bf16

    auto cdiv = [](int a, int b) { return (a + b - 1) / b; };

    // ---- graph + weight preprocessing ----
    init_deg_cnt_kernel<<<cdiv(Nn, 256), 256, 0, stream>>>(deg, cnt, Nn);
    deg_hist_kernel<<<cdiv(E, 256), 256, 0, stream>>>(edst, ew, deg, cnt, E);
    dinv_kernel<<<cdiv(Nn, 256), 256, 0, stream>>>(deg, dinv, selfnorm, Nn);
    scan_rowptr_kernel<<<1, 256, 0, stream>>>(cnt, rowptr, Nn);
    csr_fill_kernel<<<cdiv(E, 256), 256, 0, stream>>>(esrc, edst, ew, dinv, rowptr, cnt, csrc, cnorm, E);
    convert_weights_kernel<<<cdiv(CW5, 256), 256, 0, stream>>>(
        gcn_W, Wih, Whh, fc1W, fc2W, dh1W, Wtb, Wihb, Whhb, fc1Wb, fc2Wb, dh1Wb);
    init_h_kernel<<<cdiv(Nn * D, 256), 256, 0, stream>>>(hgru, hgru_bf, Nn * D);
    x_to_blocked_kernel<<<cdiv(Nn * S * D / 4, 256), 256, 0, stream>>>(x, bufA);

    // ---- batched GCN stack: all 4 snapshots at once ----
    for (int l = 0; l < L; ++l) {
        dim3 g1(D / GBN, (Nn * S) / GBM);   // (2, 625)
        gemm_bt_bf16_kernel<2, 0><<<g1, 256, 0, stream>>>(
            bufA, D, Wtb + (size_t)l * D * D, nullptr, hWb, Nn * S, D, D);
        gcn_agg_ln_relu4_kernel<<<Nn / 4, 256, 0, stream>>>(
            hWb, rowptr, csrc, cnorm, selfnorm,
            gcn_b + (size_t)l * D, ln_g + (size_t)l * D, ln_b + (size_t)l * D, bufA);
    }

    // ---- GRU loop (sequential over snapshots) ----
    for (int s = 0; s < S; ++s) {
        dim3 g2((3 * D) / GBN, cdiv(Nn, GBM));   // (6, 157)
        // gi = feats_s @ Wih^T + bih  (A rows strided: row n at bufA + (n*S+s)*D)
        gemm_bt_bf16_kernel<1, 0><<<g2, 256, 0, stream>>>(
            bufA + (size_t)s * D, S * D, Wihb, bih, gi_bf, Nn, 3 * D, D);
        gemm_bt_bf16_kernel<1, 0><<<g2, 256, 0, stream>>>(
            hgru_bf, D, Whhb, bhh, gh_bf, Nn, 3 * D, D);
        gru_gates_kernel<<<cdiv(Nn * D / 4, 256), 256, 0, stream>>>(gi_bf, gh_bf, hgru, hgru_bf);
    }

    // ---- heads (bf16 MFMA, fused gelu) ----
    {
        dim3 gf1(1, cdiv(Nn, GBM));
        gemm_bt_bf16_kernel<1, 1><<<gf1, 256, 0, stream>>>(
            hgru_bf, D, fc1Wb, fc1b, f1, Nn, 128, 256);
        gemm_bt_bf16_kernel<1, 1><<<gf1, 256, 0, stream>>>(
            f1, 128, fc2Wb, fc2b, f2, Nn, 64, 128);
        head5_bf_kernel<<<cdiv(Nn * H, 256), 256, 0, stream>>>(f2, fc3W, fc3b, out, Nn, 64);
        gemm_bt_bf16_kernel<1, 1><<<gf1, 256, 0, stream>>>(
            hgru_bf, D, dh1Wb, dh1b, d1, Nn, 64, 256);
        head5_bf_kernel<<<cdiv(Nn * H, 256), 256, 0, stream>>>(d1, dh2W, dh2b, out + (size_t)Nn * H, Nn, 64);
    }
}

// Round 5
// 881.337 us; speedup vs baseline: 4.1896x; 1.2184x over previous
//
#include <hip/hip_runtime.h>
#include <hip/hip_bf16.h>

// Problem constants (from reference)
constexpr int Nn = 20000;   // nodes
constexpr int D  = 256;     // feature dim
constexpr int S  = 4;       // snapshots
constexpr int E  = 320000;  // edges
constexpr int H  = 5;       // horizon
constexpr int L  = 3;       // GCN layers

using bf16 = __hip_bfloat16;
typedef __attribute__((ext_vector_type(8))) short v8s;   // 8 bf16 = 4 VGPRs
typedef __attribute__((ext_vector_type(4))) float v4f;   // MFMA acc

#define GLOBAL_AS __attribute__((address_space(1)))
#define LDS_AS    __attribute__((address_space(3)))

__device__ __forceinline__ float gelu_exact(float x) {
    return 0.5f * x * (1.0f + erff(x * 0.70710678118654752440f));
}
__device__ __forceinline__ unsigned short f2bu(float f) {
    bf16 h = __float2bfloat16(f);
    return *reinterpret_cast<unsigned short*>(&h);
}
__device__ __forceinline__ float b2f(unsigned short u) {
    unsigned int v = (unsigned int)u << 16;
    return __uint_as_float(v);
}

// ---------------- fused preprocessing kernels ----------------
__global__ void init_deg_cnt_kernel(float* deg, int* cnt, int n) {
    int i = blockIdx.x * blockDim.x + threadIdx.x;
    if (i < n) { deg[i] = 1.0f; cnt[i] = 0; }
}
__global__ void deg_hist_kernel(const int* __restrict__ dst, const float* __restrict__ w,
                                float* __restrict__ deg, int* __restrict__ cnt, int e) {
    int i = blockIdx.x * blockDim.x + threadIdx.x;
    if (i < e) {
        int d = dst[i];
        atomicAdd(&deg[d], w[i]);
        atomicAdd(&cnt[d], 1);
    }
}
__global__ void dinv_kernel(const float* __restrict__ deg, float* __restrict__ dinv,
                            float* __restrict__ selfnorm, int n) {
    int i = blockIdx.x * blockDim.x + threadIdx.x;
    if (i < n) {
        float dg = deg[i];
        float dv = dg > 0.0f ? rsqrtf(fmaxf(dg, 1e-5f)) : 0.0f;
        dinv[i] = dv;
        selfnorm[i] = dv * dv;
    }
}
// 1024-thread exclusive scan over cnt[0..n) -> rowptr[0..n]; zeroes cnt.
__global__ __launch_bounds__(1024) void scan_rowptr_kernel(int* __restrict__ cnt,
                                                           int* __restrict__ rowptr, int n) {
    __shared__ int wsum[16];
    __shared__ int woff[16];
    int t = threadIdx.x;
    int wave = t >> 6, lane = t & 63;
    int chunk = (n + 1023) / 1024;
    int start = t * chunk;
    int end = start + chunk; if (end > n) end = n;
    int s = 0;
    for (int i = start; i < end; ++i) s += cnt[i];
    // wave inclusive scan
    int incl = s;
#pragma unroll
    for (int off = 1; off < 64; off <<= 1) {
        int v = __shfl_up(incl, off);
        if (lane >= off) incl += v;
    }
    int excl = incl - s;
    if (lane == 63) wsum[wave] = incl;
    __syncthreads();
    if (t == 0) {
        int acc = 0;
        for (int i = 0; i < 16; ++i) { woff[i] = acc; acc += wsum[i]; }
        rowptr[n] = acc;
    }
    __syncthreads();
    int acc = woff[wave] + excl;
    for (int i = start; i < end; ++i) {
        rowptr[i] = acc; acc += cnt[i]; cnt[i] = 0;
    }
}
__global__ void csr_fill_kernel(const int* __restrict__ src, const int* __restrict__ dst,
                                const float* __restrict__ w, const float* __restrict__ dinv,
                                const int* __restrict__ rowptr,
                                int* __restrict__ cursor, int* __restrict__ csrc,
                                float* __restrict__ cnorm, int e) {
    int i = blockIdx.x * blockDim.x + threadIdx.x;
    if (i < e) {
        int sN = src[i], dN = dst[i];
        int pos = rowptr[dN] + atomicAdd(&cursor[dN], 1);
        csrc[pos] = sN;
        cnorm[pos] = dinv[sN] * w[i] * dinv[dN];
    }
}
// All weight conversions + GRU bias combine in one kernel.
constexpr int CW0 = L * D * D;          // gcn_W -> Wtb (transposed)
constexpr int CW1 = CW0 + 3 * D * D;    // Wih
constexpr int CW2 = CW1 + 3 * D * D;    // Whh
constexpr int CW3 = CW2 + 128 * 256;    // fc1W
constexpr int CW4 = CW3 + 64 * 128;     // fc2W
constexpr int CW5 = CW4 + 64 * 256;     // dh1W
constexpr int CW6 = CW5 + 4 * D;        // br, bz, big, bhg
__global__ void convert_weights_kernel(
    const float* __restrict__ gcn_W, const float* __restrict__ Wih,
    const float* __restrict__ Whh, const float* __restrict__ fc1W,
    const float* __restrict__ fc2W, const float* __restrict__ dh1W,
    const float* __restrict__ bih, const float* __restrict__ bhh,
    unsigned short* __restrict__ Wtb, unsigned short* __restrict__ Wihb,
    unsigned short* __restrict__ Whhb, unsigned short* __restrict__ fc1Wb,
    unsigned short* __restrict__ fc2Wb, unsigned short* __restrict__ dh1Wb,
    float* __restrict__ gbias)   // [4*D]: br, bz, big, bhg
{
    int i = blockIdx.x * blockDim.x + threadIdx.x;
    if (i < CW0) {
        int l = i / (D * D);
        int rem = i - l * D * D;
        int k = rem / D;
        int n = rem - k * D;
        Wtb[(size_t)l * D * D + (size_t)n * D + k] = f2bu(gcn_W[i]);
    } else if (i < CW1) { int j = i - CW0; Wihb[j]  = f2bu(Wih[j]);  }
    else if (i < CW2)   { int j = i - CW1; Whhb[j]  = f2bu(Whh[j]);  }
    else if (i < CW3)   { int j = i - CW2; fc1Wb[j] = f2bu(fc1W[j]); }
    else if (i < CW4)   { int j = i - CW3; fc2Wb[j] = f2bu(fc2W[j]); }
    else if (i < CW5)   { int j = i - CW4; dh1Wb[j] = f2bu(dh1W[j]); }
    else if (i < CW6) {
        int j = i - CW5;           // 0..1023
        int g = j >> 8, d = j & 255;
        float v;
        if (g == 0)      v = bih[d] + bhh[d];            // br
        else if (g == 1) v = bih[D + d] + bhh[D + d];    // bz
        else if (g == 2) v = bih[2 * D + d];             // big
        else             v = bhh[2 * D + d];             // bhg
        gbias[j] = v;
    }
}
__global__ void init_h_kernel(float* h, unsigned short* hb, int n) {
    int i = blockIdx.x * blockDim.x + threadIdx.x;
    if (i < n) { h[i] = 0.0f; hb[i] = 0; }
}
// x [S,N,D] f32 -> blocked [n*S+s][D] bf16, vectorized x4
__global__ __launch_bounds__(256) void x_to_blocked_kernel(const float* __restrict__ x,
                                                           unsigned short* __restrict__ out) {
    int tid = blockIdx.x * blockDim.x + threadIdx.x;   // over Nn*S*D/4
    if (tid >= Nn * S * (D / 4)) return;
    int row = tid >> 6;           // / 64 : row = s*Nn + n
    int r64 = tid & 63;
    int s = row / Nn;
    int n = row - s * Nn;
    float4 v = ((const float4*)x)[(size_t)row * 64 + r64];
    ushort4 u;
    u.x = f2bu(v.x); u.y = f2bu(v.y); u.z = f2bu(v.z); u.w = f2bu(v.w);
    ((ushort4*)out)[((size_t)(n * 4 + s)) * 64 + r64] = u;
}

// ---------------- bf16 MFMA GEMM: C = A[M,K](lda) * B[N,K]^T (+bias) -------------
// OUT_MODE 1: bf16 C[M,N] row-major (store-guarded on M and N; gelu if ACT).
// OUT_MODE 2: bf16 gather layout [node][dim][snap]: row gm = node*4+snap (M%128==0).
#define GBM 128
#define GBN 128
#define GBK 64
template<int OUT_MODE, int ACT>
__global__ __launch_bounds__(256) void gemm_bt_bf16_kernel(
    const unsigned short* __restrict__ A, int lda,
    const unsigned short* __restrict__ B,
    const float* __restrict__ bias, unsigned short* __restrict__ C,
    int M, int N, int K)
{
    __shared__ short As[GBM * GBK];
    __shared__ short Bs[GBN * GBK];
    int tid = threadIdx.x;
    int wave = tid >> 6, lane = tid & 63;
    int ln = lane & 15, quad = lane >> 4;
    int wr = wave >> 1, wc = wave & 1;
    int bm = blockIdx.y * GBM, bn = blockIdx.x * GBN;

    v4f acc[4][4];
#pragma unroll
    for (int i = 0; i < 4; ++i)
#pragma unroll
        for (int j = 0; j < 4; ++j)
            acc[i][j] = (v4f)(0.0f);

    int lrow = lane >> 3;          // 0..7 within 8-row segment
    int lcol = (lane & 7) * 8;     // bf16 col offset, 16B chunks

    for (int k0 = 0; k0 < K; k0 += GBK) {
#pragma unroll
        for (int c = 0; c < 4; ++c) {
            int seg = wave * 4 + c;           // 0..15
            int row = seg * 8 + lrow;         // 0..127
            int gm = bm + row; if (gm >= M) gm = M - 1;   // clamp: dup rows, never stored
            __builtin_amdgcn_global_load_lds(
                (const GLOBAL_AS unsigned int*)(A + (size_t)gm * lda + k0 + lcol),
                (LDS_AS unsigned int*)(&As[row * GBK + lcol]), 16, 0, 0);
            int gn = bn + row; if (gn >= N) gn = N - 1;   // clamp for N=64/128 heads
            __builtin_amdgcn_global_load_lds(
                (const GLOBAL_AS unsigned int*)(B + (size_t)gn * K + k0 + lcol),
                (LDS_AS unsigned int*)(&Bs[row * GBK + lcol]), 16, 0, 0);
        }
        __syncthreads();
#pragma unroll
        for (int ks = 0; ks < 2; ++ks) {
            v8s af[4], bfr[4];
#pragma unroll
            for (int i = 0; i < 4; ++i) {
                int row = wr * 64 + i * 16 + ln;
                af[i] = *(const v8s*)(&As[row * GBK + ks * 32 + quad * 8]);
            }
#pragma unroll
            for (int j = 0; j < 4; ++j) {
                int row = wc * 64 + j * 16 + ln;
                bfr[j] = *(const v8s*)(&Bs[row * GBK + ks * 32 + quad * 8]);
            }
#pragma unroll
            for (int i = 0; i < 4; ++i)
#pragma unroll
                for (int j = 0; j < 4; ++j)
                    acc[i][j] = __builtin_amdgcn_mfma_f32_16x16x32_bf16(af[i], bfr[j], acc[i][j], 0, 0, 0);
        }
        __syncthreads();
    }
    // epilogue: C/D layout col=lane&15, row=quad*4+reg
#pragma unroll
    for (int i = 0; i < 4; ++i) {
        int gmb = bm + wr * 64 + i * 16 + quad * 4;   // base row, multiple of 4
#pragma unroll
        for (int j = 0; j < 4; ++j) {
            int gn = bn + wc * 64 + j * 16 + ln;
            float bv = (bias && gn < N) ? bias[gn] : 0.0f;
            if (OUT_MODE == 2) {
                ushort4 u;
                u.x = f2bu(acc[i][j][0] + bv);
                u.y = f2bu(acc[i][j][1] + bv);
                u.z = f2bu(acc[i][j][2] + bv);
                u.w = f2bu(acc[i][j][3] + bv);
                int node = gmb >> 2;
                *(ushort4*)(C + ((size_t)node * D + gn) * 4) = u;
            } else {
                if (gn < N) {
#pragma unroll
                    for (int r = 0; r < 4; ++r) {
                        int gm = gmb + r;
                        if (gm < M) {
                            float v = acc[i][j][r] + bv;
                            if (ACT == 1) v = gelu_exact(v);
                            C[(size_t)gm * N + gn] = f2bu(v);
                        }
                    }
                }
            }
        }
    }
}

// ---------------- fused GRU step: both GEMMs + gates in one kernel ----------------
// h' = (1-z)*n + z*h ;  r/z accumulate x@Wi + h@Wh in SHARED accumulators;
// n = tanh(IG + r*HG) with IG = x@Wig + big, HG = h@Whg + bhg.
// Block: 256 thr = 4 waves (2x2); tile 64 nodes x 64 dims; K=256 per phase.
__global__ __launch_bounds__(256) void gru_fused_kernel(
    const unsigned short* __restrict__ feat, int fstride,   // phase-0 A
    const unsigned short* __restrict__ hbf,                 // phase-1 A  [node][D]
    const unsigned short* __restrict__ Wihb,                // [3*D][D]
    const unsigned short* __restrict__ Whhb,
    const float* __restrict__ gbias,                        // [4*D] br,bz,big,bhg
    float* __restrict__ h, unsigned short* __restrict__ hb, int write_f32)
{
    __shared__ short As[64 * 64];     // 8 KB
    __shared__ short Bs[192 * 64];    // 24 KB (3 gates x 64 dims)
    int tid = threadIdx.x;
    int wave = tid >> 6, lane = tid & 63;
    int ln = lane & 15, quad = lane >> 4;
    int wm = wave >> 1, wn = wave & 1;
    int bm = blockIdx.y * 64;
    int bn = blockIdx.x * 64;        // dim block

    v4f accR[2][2], accZ[2][2], accG[2][2], accHG[2][2];
#pragma unroll
    for (int mi = 0; mi < 2; ++mi)
#pragma unroll
        for (int nj = 0; nj < 2; ++nj) {
            accR[mi][nj] = (v4f)(0.0f); accZ[mi][nj] = (v4f)(0.0f);
            accG[mi][nj] = (v4f)(0.0f); accHG[mi][nj] = (v4f)(0.0f);
        }

    int lrow = lane >> 3, lcol = (lane & 7) * 8;

    for (int phase = 0; phase < 2; ++phase) {
        const unsigned short* A = phase ? hbf : feat;
        int astr = phase ? D : fstride;
        const unsigned short* W = phase ? Whhb : Wihb;
        for (int k0 = 0; k0 < D; k0 += 64) {
            // stage A: 64 rows x 64 cols
#pragma unroll
            for (int c = 0; c < 2; ++c) {
                int row = wave * 16 + c * 8 + lrow;
                int gm = bm + row; if (gm >= Nn) gm = Nn - 1;
                __builtin_amdgcn_global_load_lds(
                    (const GLOBAL_AS unsigned int*)(A + (size_t)gm * astr + k0 + lcol),
                    (LDS_AS unsigned int*)(&As[row * 64 + lcol]), 16, 0, 0);
            }
            // stage B: 3 gates x 64 dim-rows x 64 cols
#pragma unroll
            for (int c = 0; c < 6; ++c) {
                int row = wave * 48 + c * 8 + lrow;   // 0..191
                int g = row >> 6, dloc = row & 63;
                __builtin_amdgcn_global_load_lds(
                    (const GLOBAL_AS unsigned int*)(W + ((size_t)(g * D + bn + dloc)) * D + k0 + lcol),
                    (LDS_AS unsigned int*)(&Bs[row * 64 + lcol]), 16, 0, 0);
            }
            __syncthreads();
#pragma unroll
            for (int ks = 0; ks < 2; ++ks) {
                v8s am[2];
#pragma unroll
                for (int mi = 0; mi < 2; ++mi)
                    am[mi] = *(const v8s*)(&As[(wm * 32 + mi * 16 + ln) * 64 + ks * 32 + quad * 8]);
#pragma unroll
                for (int g = 0; g < 3; ++g) {
#pragma unroll
                    for (int nj = 0; nj < 2; ++nj) {
                        v8s bf = *(const v8s*)(&Bs[(g * 64 + wn * 32 + nj * 16 + ln) * 64 + ks * 32 + quad * 8]);
#pragma unroll
                        for (int mi = 0; mi < 2; ++mi) {
                            if (g == 0)
                                accR[mi][nj] = __builtin_amdgcn_mfma_f32_16x16x32_bf16(am[mi], bf, accR[mi][nj], 0, 0, 0);
                            else if (g == 1)
                                accZ[mi][nj] = __builtin_amdgcn_mfma_f32_16x16x32_bf16(am[mi], bf, accZ[mi][nj], 0, 0, 0);
                            else if (phase == 0)
                                accG[mi][nj] = __builtin_amdgcn_mfma_f32_16x16x32_bf16(am[mi], bf, accG[mi][nj], 0, 0, 0);
                            else
                                accHG[mi][nj] = __builtin_amdgcn_mfma_f32_16x16x32_bf16(am[mi], bf, accHG[mi][nj], 0, 0, 0);
                        }
                    }
                }
            }
            __syncthreads();
        }
    }
    // epilogue: gates + h update. C/D: col=ln (dim), row=quad*4+r (node)
#pragma unroll
    for (int mi = 0; mi < 2; ++mi) {
        int gm0 = bm + wm * 32 + mi * 16 + quad * 4;
#pragma unroll
        for (int nj = 0; nj < 2; ++nj) {
            int gn = bn + wn * 32 + nj * 16 + ln;
            float vbr = gbias[gn], vbz = gbias[D + gn];
            float vbig = gbias[2 * D + gn], vbhg = gbias[3 * D + gn];
#pragma unroll
            for (int r = 0; r < 4; ++r) {
                int gm = gm0 + r;
                if (gm < Nn) {
                    float rv = 1.0f / (1.0f + expf(-(accR[mi][nj][r] + vbr)));
                    float zv = 1.0f / (1.0f + expf(-(accZ[mi][nj][r] + vbz)));
                    float nv = tanhf(accG[mi][nj][r] + vbig + rv * (accHG[mi][nj][r] + vbhg));
                    float hold = h[(size_t)gm * D + gn];
                    float hv = (1.0f - zv) * nv + zv * hold;
                    if (write_f32) h[(size_t)gm * D + gn] = hv;
                    hb[(size_t)gm * D + gn] = f2bu(hv);
                }
            }
        }
    }
}

// ------- GCN aggregate (4 snapshots) + bias + LayerNorm + ReLU, one WAVE/node ----
__global__ __launch_bounds__(256) void gcn_agg_ln_relu4_kernel(
    const unsigned short* __restrict__ hWb, const int* __restrict__ rowptr,
    const int* __restrict__ csrc, const float* __restrict__ cnorm,
    const float* __restrict__ selfnorm,
    const float* __restrict__ gcn_b, const float* __restrict__ ln_g,
    const float* __restrict__ ln_b, unsigned short* __restrict__ out)
{
    int wave = threadIdx.x >> 6, lane = threadIdx.x & 63;
    int i = blockIdx.x * 4 + wave;
    const ushort4* tbl = (const ushort4*)hWb;

    float acc[4][4];   // [q dim-seg][s snap]
    {
        float w = selfnorm[i];
#pragma unroll
        for (int q = 0; q < 4; ++q) {
            ushort4 u = tbl[(size_t)i * D + lane + q * 64];
            acc[q][0] = w * b2f(u.x); acc[q][1] = w * b2f(u.y);
            acc[q][2] = w * b2f(u.z); acc[q][3] = w * b2f(u.w);
        }
    }
    int beg = rowptr[i], end = rowptr[i + 1];
    int p = beg;
    for (; p + 1 < end; p += 2) {
        int sA = csrc[p], sB = csrc[p + 1];
        float wA = cnorm[p], wB = cnorm[p + 1];
        ushort4 uA[4], uB[4];
#pragma unroll
        for (int q = 0; q < 4; ++q) uA[q] = tbl[(size_t)sA * D + lane + q * 64];
#pragma unroll
        for (int q = 0; q < 4; ++q) uB[q] = tbl[(size_t)sB * D + lane + q * 64];
#pragma unroll
        for (int q = 0; q < 4; ++q) {
            acc[q][0] = fmaf(wA, b2f(uA[q].x), acc[q][0]);
            acc[q][1] = fmaf(wA, b2f(uA[q].y), acc[q][1]);
            acc[q][2] = fmaf(wA, b2f(uA[q].z), acc[q][2]);
            acc[q][3] = fmaf(wA, b2f(uA[q].w), acc[q][3]);
            acc[q][0] = fmaf(wB, b2f(uB[q].x), acc[q][0]);
            acc[q][1] = fmaf(wB, b2f(uB[q].y), acc[q][1]);
            acc[q][2] = fmaf(wB, b2f(uB[q].z), acc[q][2]);
            acc[q][3] = fmaf(wB, b2f(uB[q].w), acc[q][3]);
        }
    }
    if (p < end) {
        int sA = csrc[p]; float wA = cnorm[p];
#pragma unroll
        for (int q = 0; q < 4; ++q) {
            ushort4 u = tbl[(size_t)sA * D + lane + q * 64];
            acc[q][0] = fmaf(wA, b2f(u.x), acc[q][0]);
            acc[q][1] = fmaf(wA, b2f(u.y), acc[q][1]);
            acc[q][2] = fmaf(wA, b2f(u.z), acc[q][2]);
            acc[q][3] = fmaf(wA, b2f(u.w), acc[q][3]);
        }
    }
#pragma unroll
    for (int q = 0; q < 4; ++q) {
        float bb = gcn_b[lane + q * 64];
        acc[q][0] += bb; acc[q][1] += bb; acc[q][2] += bb; acc[q][3] += bb;
    }
    float s1[4], s2[4];
#pragma unroll
    for (int s = 0; s < 4; ++s) {
        s1[s] = acc[0][s] + acc[1][s] + acc[2][s] + acc[3][s];
        s2[s] = acc[0][s] * acc[0][s] + acc[1][s] * acc[1][s]
              + acc[2][s] * acc[2][s] + acc[3][s] * acc[3][s];
    }
#pragma unroll
    for (int off = 32; off > 0; off >>= 1) {
#pragma unroll
        for (int s = 0; s < 4; ++s) {
            s1[s] += __shfl_xor(s1[s], off);
            s2[s] += __shfl_xor(s2[s], off);
        }
    }
    const float inv = 1.0f / D;
    float m[4], rr[4];
#pragma unroll
    for (int s = 0; s < 4; ++s) {
        m[s] = s1[s] * inv;
        rr[s] = rsqrtf(s2[s] * inv - m[s] * m[s] + 1e-5f);
    }
    size_t ob = (size_t)(i << 2) * D;
#pragma unroll
    for (int q = 0; q < 4; ++q) {
        int d = lane + q * 64;
        float g = ln_g[d], lb = ln_b[d];
#pragma unroll
        for (int s = 0; s < 4; ++s) {
            float y = (acc[q][s] - m[s]) * rr[s] * g + lb;
            out[ob + (size_t)s * D + d] = f2bu(fmaxf(y, 0.0f));
        }
    }
}

// ---------------- small output head: C[M,5] = A_bf16[M,K] * W[5,K]^T + b ----------
__global__ void head5_bf_kernel(const unsigned short* __restrict__ A,
                                const float* __restrict__ W,
                                const float* __restrict__ b, float* __restrict__ C,
                                int M, int K) {
    int idx = blockIdx.x * blockDim.x + threadIdx.x;
    if (idx >= M * H) return;
    int m = idx / H;
    int h = idx - m * H;
    const ushort4* ar = (const ushort4*)(A + (size_t)m * K);
    const float* wr = W + (size_t)h * K;
    float s = 0.0f;
    for (int k4 = 0; k4 < K / 4; ++k4) {
        ushort4 u = ar[k4];
        s = fmaf(b2f(u.x), wr[4 * k4 + 0], s);
        s = fmaf(b2f(u.y), wr[4 * k4 + 1], s);
        s = fmaf(b2f(u.z), wr[4 * k4 + 2], s);
        s = fmaf(b2f(u.w), wr[4 * k4 + 3], s);
    }
    C[idx] = s + b[h];
}

extern "C" void kernel_launch(void* const* d_in, const int* in_sizes, int n_in,
                              void* d_out, int out_size, void* d_ws, size_t ws_size,
                              hipStream_t stream)
{
    const float* x     = (const float*)d_in[0];
    const int*   esrc  = (const int*)d_in[1];
    const int*   edst  = (const int*)d_in[2];
    const float* ew    = (const float*)d_in[3];
    const float* gcn_W = (const float*)d_in[4];
    const float* gcn_b = (const float*)d_in[5];
    const float* ln_g  = (const float*)d_in[6];
    const float* ln_b  = (const float*)d_in[7];
    const float* Wih   = (const float*)d_in[8];
    const float* Whh   = (const float*)d_in[9];
    const float* bih   = (const float*)d_in[10];
    const float* bhh   = (const float*)d_in[11];
    const float* fc1W  = (const float*)d_in[12];
    const float* fc1b  = (const float*)d_in[13];
    const float* fc2W  = (const float*)d_in[14];
    const float* fc2b  = (const float*)d_in[15];
    const float* fc3W  = (const float*)d_in[16];
    const float* fc3b  = (const float*)d_in[17];
    const float* dh1W  = (const float*)d_in[18];
    const float* dh1b  = (const float*)d_in[19];
    const float* dh2W  = (const float*)d_in[20];
    const float* dh2b  = (const float*)d_in[21];

    float* out = (float*)d_out;   // [Nn*H forecast][Nn*H direction]

    // workspace carve-out (aligned to 256B); total ~128 MB
    char* p = (char*)d_ws;
    auto alloc = [&](size_t bytes) -> void* {
        void* r = (void*)p;
        p += (bytes + 255) & ~(size_t)255;
        return r;
    };
    float* deg      = (float*)alloc((size_t)Nn * 4);
    float* dinv     = (float*)alloc((size_t)Nn * 4);
    float* selfnorm = (float*)alloc((size_t)Nn * 4);
    int*   rowptr   = (int*)alloc((size_t)(Nn + 1) * 4);
    int*   cnt      = (int*)alloc((size_t)Nn * 4);
    int*   csrc     = (int*)alloc((size_t)E * 4);
    float* cnorm    = (float*)alloc((size_t)E * 4);
    unsigned short* Wtb   = (unsigned short*)alloc((size_t)L * D * D * 2);
    unsigned short* Wihb  = (unsigned short*)alloc((size_t)3 * D * D * 2);
    unsigned short* Whhb  = (unsigned short*)alloc((size_t)3 * D * D * 2);
    unsigned short* fc1Wb = (unsigned short*)alloc((size_t)128 * 256 * 2);
    unsigned short* fc2Wb = (unsigned short*)alloc((size_t)64 * 128 * 2);
    unsigned short* dh1Wb = (unsigned short*)alloc((size_t)64 * 256 * 2);
    float* gbias    = (float*)alloc((size_t)4 * D * 4);
    unsigned short* bufA  = (unsigned short*)alloc((size_t)Nn * S * D * 2);    // 41MB
    unsigned short* hWb   = (unsigned short*)alloc((size_t)Nn * D * S * 2);    // 41MB
    float* hgru     = (float*)alloc((size_t)Nn * D * 4);                       // 20.5MB
    unsigned short* hgru_bf = (unsigned short*)alloc((size_t)Nn * D * 2);      // 10.2MB
    unsigned short* f1 = (unsigned short*)alloc((size_t)Nn * 128 * 2);         // 5.1MB
    unsigned short* f2 = (unsigned short*)alloc((size_t)Nn * 64 * 2);          // 2.6MB
    unsigned short* d1 = (unsigned short*)alloc((size_t)Nn * 64 * 2);          // 2.6MB

    auto cdiv = [](int a, int b) { return (a + b - 1) / b; };

    // ---- graph + weight preprocessing ----
    init_deg_cnt_kernel<<<cdiv(Nn, 256), 256, 0, stream>>>(deg, cnt, Nn);
    deg_hist_kernel<<<cdiv(E, 256), 256, 0, stream>>>(edst, ew, deg, cnt, E);
    dinv_kernel<<<cdiv(Nn, 256), 256, 0, stream>>>(deg, dinv, selfnorm, Nn);
    scan_rowptr_kernel<<<1, 1024, 0, stream>>>(cnt, rowptr, Nn);
    csr_fill_kernel<<<cdiv(E, 256), 256, 0, stream>>>(esrc, edst, ew, dinv, rowptr, cnt, csrc, cnorm, E);
    convert_weights_kernel<<<cdiv(CW6, 256), 256, 0, stream>>>(
        gcn_W, Wih, Whh, fc1W, fc2W, dh1W, bih, bhh,
        Wtb, Wihb, Whhb, fc1Wb, fc2Wb, dh1Wb, gbias);
    init_h_kernel<<<cdiv(Nn * D, 256), 256, 0, stream>>>(hgru, hgru_bf, Nn * D);
    x_to_blocked_kernel<<<cdiv(Nn * S * D / 4, 256), 256, 0, stream>>>(x, bufA);

    // ---- batched GCN stack: all 4 snapshots at once ----
    for (int l = 0; l < L; ++l) {
        dim3 g1(D / GBN, (Nn * S) / GBM);   // (2, 625)
        gemm_bt_bf16_kernel<2, 0><<<g1, 256, 0, stream>>>(
            bufA, D, Wtb + (size_t)l * D * D, nullptr, hWb, Nn * S, D, D);
        gcn_agg_ln_relu4_kernel<<<Nn / 4, 256, 0, stream>>>(
            hWb, rowptr, csrc, cnorm, selfnorm,
            gcn_b + (size_t)l * D, ln_g + (size_t)l * D, ln_b + (size_t)l * D, bufA);
    }

    // ---- fused GRU loop (1 kernel per snapshot) ----
    for (int s = 0; s < S; ++s) {
        dim3 g2(D / 64, cdiv(Nn, 64));   // (4, 313)
        gru_fused_kernel<<<g2, 256, 0, stream>>>(
            bufA + (size_t)s * D, S * D, hgru_bf, Wihb, Whhb, gbias,
            hgru, hgru_bf, (s < S - 1) ? 1 : 0);
    }

    // ---- heads (bf16 MFMA, fused gelu) ----
    {
        dim3 gf1(1, cdiv(Nn, GBM));
        gemm_bt_bf16_kernel<1, 1><<<gf1, 256, 0, stream>>>(
            hgru_bf, D, fc1Wb, fc1b, f1, Nn, 128, 256);
        gemm_bt_bf16_kernel<1, 1><<<gf1, 256, 0, stream>>>(
            f1, 128, fc2Wb, fc2b, f2, Nn, 64, 128);
        head5_bf_kernel<<<cdiv(Nn * H, 256), 256, 0, stream>>>(f2, fc3W, fc3b, out, Nn, 64);
        gemm_bt_bf16_kernel<1, 1><<<gf1, 256, 0, stream>>>(
            hgru_bf, D, dh1Wb, dh1b, d1, Nn, 64, 256);
        head5_bf_kernel<<<cdiv(Nn * H, 256), 256, 0, stream>>>(d1, dh2W, dh2b, out + (size_t)Nn * H, Nn, 64);
    }
}